// Round 3
// baseline (1100.966 us; speedup 1.0000x reference)
//
#include <hip/hip_runtime.h>
#include <math.h>

#define BB 8
#define LL 2048
#define DD 512
#define HH 8
#define DHH 64
#define KD 8
#define MM (BB*LL)   // 16384

typedef _Float16 f16x4 __attribute__((ext_vector_type(4)));
typedef _Float16 f16x8 __attribute__((ext_vector_type(8)));
typedef float    f32x4 __attribute__((ext_vector_type(4)));

// ---------------- MFMA GEMM: C = X @ W^T + bias ----------------
// NPROD==1: plain fp16. NPROD==3: hi/lo split for the score path.
template<int NPROD>
__global__ __launch_bounds__(256, 2) void gemm_mfma(const float* __restrict__ X,
                                                    const float* __restrict__ W,
                                                    const float* __restrict__ bias,
                                                    float* __restrict__ C,
                                                    int mode) {
    __shared__ __align__(16) _Float16 lds[(NPROD == 3) ? 20480 : 10240];
    _Float16* Ah = lds;
    _Float16* Bh = lds + 5120;
    _Float16* Al = (NPROD == 3) ? lds + 10240 : lds;
    _Float16* Bl = (NPROD == 3) ? lds + 15360 : lds;

    const int t    = threadIdx.x;
    const int m0   = blockIdx.y * 128;
    const int n0   = blockIdx.x * 128;
    const int srow = t >> 3;
    const int scol = (t & 7) * 4;
    const int wave = t >> 6;
    const int lane = t & 63;
    const int wm   = (wave >> 1) * 64;
    const int wn   = (wave & 1) * 64;
    const int lm   = lane & 15;
    const int quad = lane >> 4;

    f32x4 acc0[4][4] = {};
    f32x4 acc1[4][4] = {};

    float4 ar[4], br[4];
#pragma unroll
    for (int p = 0; p < 4; p++) {
        ar[p] = *(const float4*)(X + (size_t)(m0 + p * 32 + srow) * 512 + scol);
        br[p] = *(const float4*)(W + (size_t)(n0 + p * 32 + srow) * 512 + scol);
    }

    for (int k0 = 0; k0 < 512; k0 += 32) {
        __syncthreads();
#pragma unroll
        for (int p = 0; p < 4; p++) {
            const int row = p * 32 + srow;
            const float xa[4] = {ar[p].x, ar[p].y, ar[p].z, ar[p].w};
            const float xb[4] = {br[p].x, br[p].y, br[p].z, br[p].w};
            f16x4 ha, hb, la, lb;
#pragma unroll
            for (int j = 0; j < 4; j++) {
                const _Float16 h1 = (_Float16)xa[j];
                const _Float16 h2 = (_Float16)xb[j];
                ha[j] = h1; hb[j] = h2;
                if (NPROD == 3) {
                    la[j] = (_Float16)((xa[j] - (float)h1) * 512.0f);
                    lb[j] = (_Float16)((xb[j] - (float)h2) * 512.0f);
                }
            }
            *(f16x4*)&Ah[row * 40 + scol] = ha;
            *(f16x4*)&Bh[row * 40 + scol] = hb;
            if (NPROD == 3) {
                *(f16x4*)&Al[row * 40 + scol] = la;
                *(f16x4*)&Bl[row * 40 + scol] = lb;
            }
        }
        __syncthreads();

        if (k0 + 32 < 512) {
#pragma unroll
            for (int p = 0; p < 4; p++) {
                ar[p] = *(const float4*)(X + (size_t)(m0 + p * 32 + srow) * 512 + k0 + 32 + scol);
                br[p] = *(const float4*)(W + (size_t)(n0 + p * 32 + srow) * 512 + k0 + 32 + scol);
            }
        }

        f16x8 afh[4], bf[4];
#pragma unroll
        for (int mt = 0; mt < 4; mt++)
            afh[mt] = *(f16x8*)&Ah[(wm + mt * 16 + lm) * 40 + quad * 8];
#pragma unroll
        for (int nt = 0; nt < 4; nt++)
            bf[nt] = *(f16x8*)&Bh[(wn + nt * 16 + lm) * 40 + quad * 8];

#pragma unroll
        for (int mt = 0; mt < 4; mt++)
#pragma unroll
            for (int nt = 0; nt < 4; nt++)
                acc0[mt][nt] = __builtin_amdgcn_mfma_f32_16x16x32_f16(afh[mt], bf[nt], acc0[mt][nt], 0, 0, 0);

        if (NPROD == 3) {
            f16x8 afl[4];
#pragma unroll
            for (int mt = 0; mt < 4; mt++)
                afl[mt] = *(f16x8*)&Al[(wm + mt * 16 + lm) * 40 + quad * 8];
#pragma unroll
            for (int mt = 0; mt < 4; mt++)
#pragma unroll
                for (int nt = 0; nt < 4; nt++)
                    acc1[mt][nt] = __builtin_amdgcn_mfma_f32_16x16x32_f16(afl[mt], bf[nt], acc1[mt][nt], 0, 0, 0);
#pragma unroll
            for (int nt = 0; nt < 4; nt++)
                bf[nt] = *(f16x8*)&Bl[(wn + nt * 16 + lm) * 40 + quad * 8];
#pragma unroll
            for (int mt = 0; mt < 4; mt++)
#pragma unroll
                for (int nt = 0; nt < 4; nt++)
                    acc1[mt][nt] = __builtin_amdgcn_mfma_f32_16x16x32_f16(afh[mt], bf[nt], acc1[mt][nt], 0, 0, 0);
        }
    }

#pragma unroll
    for (int mt = 0; mt < 4; mt++) {
#pragma unroll
        for (int nt = 0; nt < 4; nt++) {
            const int n = n0 + wn + nt * 16 + lm;
            const float bv = bias[n];
#pragma unroll
            for (int r = 0; r < 4; r++) {
                const int m = m0 + wm + mt * 16 + quad * 4 + r;
                float val = acc0[mt][nt][r] + bv;
                if (NPROD == 3) val += acc1[mt][nt][r] * (1.0f / 512.0f);
                const int b_idx = m >> 11;
                const int l     = m & 2047;
                size_t addr;
                if (mode == 0)      addr = (size_t)m * 512 + n;
                else if (mode == 1) addr = ((size_t)(b_idx * 512 + n)) * 2048 + l;
                else                addr = (size_t)b_idx * 1048576 + (size_t)(n >> 6) * 131072
                                           + (size_t)l * 64 + (n & 63);
                C[addr] = val;
            }
        }
    }
}

// ============== register-resident radix-8 DIF forward FFT (N=2048) ==============
// Each thread owns 8 float2 in registers; butterflies are register-only.
// LDS only for 3 ownership exchanges + final store. DIF: natural in, bit-rev out.
// Padded LDS map: ≤2-way bank aliasing on all exchange patterns (2-way is free).
#define PADI(i) ((i) + ((((i) >> 5)) << 2))

__device__ inline float2 cmul2(float2 a, float2 w) {
    return make_float2(a.x * w.x - a.y * w.y, a.x * w.y + a.y * w.x);
}
__device__ inline float2 cadd2(float2 a, float2 b) { return make_float2(a.x + b.x, a.y + b.y); }
__device__ inline float2 csub2(float2 a, float2 b) { return make_float2(a.x - b.x, a.y - b.y); }

__global__ __launch_bounds__(256) void fft_fwd(const float* __restrict__ qT,
                                               const float* __restrict__ kT,
                                               float* __restrict__ spec) {
    const int seq = blockIdx.x;      // (b*H + h)*64 + dh
    const int t   = threadIdx.x;
    __shared__ float2 Zs[2300];      // PADI(2047) = 2299
    __shared__ float2 Wt[1024];      // Wt[j] = exp(-2*pi*i*j/2048)

#pragma unroll
    for (int s = 0; s < 4; s++) {
        const int j = t + s * 256;
        float sv, cv;
        __sincosf(2.0f * (float)M_PI * (float)j / 2048.0f, &sv, &cv);
        Wt[j] = make_float2(cv, -sv);
    }

    const float* qp = qT + (size_t)seq * 2048;
    const float* kp = kT + (size_t)seq * 2048;
    float2 z[8];
#pragma unroll
    for (int s = 0; s < 8; s++) z[s] = make_float2(qp[t + 256 * s], kp[t + 256 * s]);
    __syncthreads();   // Wt ready

    // ---- round 1: ownership i = t + 256*s (bits 10,9,8), jb = t ----
#pragma unroll
    for (int sp = 0; sp < 4; sp++) {               // h=1024, exp = j
        float2 u = z[sp], v = z[sp + 4];
        z[sp]     = cadd2(u, v);
        z[sp + 4] = cmul2(csub2(u, v), Wt[t + 256 * sp]);
    }
#pragma unroll
    for (int base = 0; base < 8; base += 4)        // h=512, exp = 2j
#pragma unroll
        for (int q2 = 0; q2 < 2; q2++) {
            float2 u = z[base + q2], v = z[base + q2 + 2];
            z[base + q2]     = cadd2(u, v);
            z[base + q2 + 2] = cmul2(csub2(u, v), Wt[2 * (t + 256 * q2)]);
        }
    {
        const float2 w = Wt[4 * t];                // h=256, exp = 4j (j = t)
#pragma unroll
        for (int e = 0; e < 8; e += 2) {
            float2 u = z[e], v = z[e + 1];
            z[e]     = cadd2(u, v);
            z[e + 1] = cmul2(csub2(u, v), w);
        }
    }

    // exchange 1 -> ownership i = low5 + 32*s + 256*hi3
#pragma unroll
    for (int s = 0; s < 8; s++) Zs[PADI(t + 256 * s)] = z[s];
    __syncthreads();
    const int low5 = t & 31, hi3 = t >> 5;
#pragma unroll
    for (int s = 0; s < 8; s++) z[s] = Zs[PADI(low5 + 32 * s + 256 * hi3)];
    __syncthreads();

    // ---- round 2 (bits 7,6,5), jb = low5 ----
#pragma unroll
    for (int sp = 0; sp < 4; sp++) {               // h=128, exp = 8j
        float2 u = z[sp], v = z[sp + 4];
        z[sp]     = cadd2(u, v);
        z[sp + 4] = cmul2(csub2(u, v), Wt[8 * (low5 + 32 * sp)]);
    }
#pragma unroll
    for (int base = 0; base < 8; base += 4)        // h=64, exp = 16j
#pragma unroll
        for (int q2 = 0; q2 < 2; q2++) {
            float2 u = z[base + q2], v = z[base + q2 + 2];
            z[base + q2]     = cadd2(u, v);
            z[base + q2 + 2] = cmul2(csub2(u, v), Wt[16 * (low5 + 32 * q2)]);
        }
    {
        const float2 w = Wt[32 * low5];            // h=32, exp = 32j
#pragma unroll
        for (int e = 0; e < 8; e += 2) {
            float2 u = z[e], v = z[e + 1];
            z[e]     = cadd2(u, v);
            z[e + 1] = cmul2(csub2(u, v), w);
        }
    }

    // exchange 2 -> ownership i = low2 + 4*s + 32*hi6
#pragma unroll
    for (int s = 0; s < 8; s++) Zs[PADI(low5 + 32 * s + 256 * hi3)] = z[s];
    __syncthreads();
    const int low2 = t & 3, hi6 = t >> 2;
#pragma unroll
    for (int s = 0; s < 8; s++) z[s] = Zs[PADI(low2 + 4 * s + 32 * hi6)];
    __syncthreads();

    // ---- round 3 (bits 4,3,2), jb = low2 ----
#pragma unroll
    for (int sp = 0; sp < 4; sp++) {               // h=16, exp = 64j
        float2 u = z[sp], v = z[sp + 4];
        z[sp]     = cadd2(u, v);
        z[sp + 4] = cmul2(csub2(u, v), Wt[64 * (low2 + 4 * sp)]);
    }
#pragma unroll
    for (int base = 0; base < 8; base += 4)        // h=8, exp = 128j
#pragma unroll
        for (int q2 = 0; q2 < 2; q2++) {
            float2 u = z[base + q2], v = z[base + q2 + 2];
            z[base + q2]     = cadd2(u, v);
            z[base + q2 + 2] = cmul2(csub2(u, v), Wt[128 * (low2 + 4 * q2)]);
        }
    {
        const float2 w = Wt[256 * low2];           // h=4, exp = 256j
#pragma unroll
        for (int e = 0; e < 8; e += 2) {
            float2 u = z[e], v = z[e + 1];
            z[e]     = cadd2(u, v);
            z[e + 1] = cmul2(csub2(u, v), w);
        }
    }

    // exchange 3 -> ownership i = 8*t + s (bits 2,1,0)
#pragma unroll
    for (int s = 0; s < 8; s++) Zs[PADI(low2 + 4 * s + 32 * hi6)] = z[s];
    __syncthreads();
#pragma unroll
    for (int s = 0; s < 8; s++) z[s] = Zs[PADI(8 * t + s)];
    __syncthreads();

    // ---- round 4 (bits 1,0): twiddles are 1 / -i only ----
#pragma unroll
    for (int base = 0; base < 8; base += 4) {
        {   // h=2, j=0
            float2 u = z[base], v = z[base + 2];
            z[base]     = cadd2(u, v);
            z[base + 2] = csub2(u, v);
        }
        {   // h=2, j=1: *( -i )
            float2 u = z[base + 1], v = z[base + 3];
            float2 d = csub2(u, v);
            z[base + 1] = cadd2(u, v);
            z[base + 3] = make_float2(d.y, -d.x);
        }
    }
#pragma unroll
    for (int e = 0; e < 8; e += 2) {               // h=1
        float2 u = z[e], v = z[e + 1];
        z[e]     = cadd2(u, v);
        z[e + 1] = csub2(u, v);
    }

    // final store: position p holds Z[rev11(p)] (identity indexing)
#pragma unroll
    for (int s = 0; s < 8; s++) Zs[8 * t + s] = z[s];
    __syncthreads();

    // unpack q+ik and accumulate P(f) = Qf*conj(Kf) into full 2048-bin spec
    const int bh = seq >> 6;
    float* sp2 = spec + (size_t)bh * 4096;
#pragma unroll
    for (int s = 0; s < 8; s++) {
        const int p  = t + 256 * s;
        const int f  = (int)(__brev((unsigned)p) >> 21);
        const int fm = (2048 - f) & 2047;
        const int p2 = (int)(__brev((unsigned)fm) >> 21);
        const float2 zf = Zs[p];
        const float2 zm = Zs[p2];
        const float qr = 0.5f * (zf.x + zm.x);
        const float qi = 0.5f * (zf.y - zm.y);
        const float kr = 0.5f * (zf.y + zm.y);
        const float ki = 0.5f * (zm.x - zf.x);
        const float pr = qr * kr + qi * ki;
        const float pi = qi * kr - qr * ki;
        if (f != 0) {   // DC bin stays zero (mean subtraction)
            atomicAdd(&sp2[2 * f + 0], pr);
            atomicAdd(&sp2[2 * f + 1], pi);
        }
    }
}

// ---------------- radix-2 LDS FFT (kept for the cheap 64-block inverse) ----------------
__device__ inline void build_twiddle(float2* Wt, int tid, float sign) {
#pragma unroll
    for (int s = 0; s < 4; s++) {
        const int j = tid + s * 256;
        const float a = 2.0f * (float)M_PI * (float)j / 2048.0f;
        float sv, cv;
        __sincosf(a, &sv, &cv);
        Wt[j] = make_float2(cv, sign * sv);
    }
}

__device__ inline void fft2048(float2* Z, const float2* Wt, int tid) {
    float2 tmp[8];
    int dst[8];
#pragma unroll
    for (int s = 0; s < 8; s++) {
        const int i = tid + s * 256;
        dst[s] = (int)(__brev((unsigned)i) >> 21);
        tmp[s] = Z[i];
    }
    __syncthreads();
#pragma unroll
    for (int s = 0; s < 8; s++) Z[dst[s]] = tmp[s];
    __syncthreads();

    for (int st = 0; st < 11; st++) {
        const int half = 1 << st;
        const int shift = 10 - st;
#pragma unroll
        for (int r = 0; r < 4; r++) {
            const int m   = tid + r * 256;
            const int grp = m >> st;
            const int pos = m & (half - 1);
            const int i0  = (grp << (st + 1)) + pos;
            const int i1  = i0 + half;
            const float2 w = Wt[pos << shift];
            const float2 a = Z[i0];
            const float2 b = Z[i1];
            const float tr = b.x * w.x - b.y * w.y;
            const float ti = b.x * w.y + b.y * w.x;
            Z[i0] = make_float2(a.x + tr, a.y + ti);
            Z[i1] = make_float2(a.x - tr, a.y - ti);
        }
        __syncthreads();
    }
}

// inverse + top-8: one block per (b,h); spec is full 2048 bins, natural order
__global__ __launch_bounds__(256) void fft_inv_topk(const float* __restrict__ spec,
                                                    int* __restrict__ delays,
                                                    float* __restrict__ weights) {
    const int bh  = blockIdx.x;
    const int tid = threadIdx.x;
    __shared__ float2 Z[2048];
    __shared__ float2 Wt[1024];
    __shared__ float  corrS[2048];
    __shared__ float  rv[256];
    __shared__ int    ri[256];
    __shared__ float  vals[KD];
    __shared__ int    inds[KD];

    build_twiddle(Wt, tid, +1.0f);

    const float* sp = spec + (size_t)bh * 4096;
#pragma unroll
    for (int s = 0; s < 8; s++) {
        const int f = tid + s * 256;
        Z[f] = make_float2(sp[2 * f], sp[2 * f + 1]);
    }
    __syncthreads();
    fft2048(Z, Wt, tid);

    const float scale = 1.0f / (2048.0f * 64.0f);
#pragma unroll
    for (int s = 0; s < 8; s++) {
        const int i = tid + s * 256;
        corrS[i] = Z[i].x * scale;
    }
    __syncthreads();

    for (int k = 0; k < KD; k++) {
        float best = -1e30f;
        int   bi   = 1 << 30;
        for (int i = tid; i < 2048; i += 256) {
            const float v = corrS[i];
            if (v > best || (v == best && i < bi)) { best = v; bi = i; }
        }
        rv[tid] = best;
        ri[tid] = bi;
        __syncthreads();
        for (int off = 128; off > 0; off >>= 1) {
            if (tid < off) {
                const float v2 = rv[tid + off];
                const int   i2 = ri[tid + off];
                if (v2 > rv[tid] || (v2 == rv[tid] && i2 < ri[tid])) {
                    rv[tid] = v2; ri[tid] = i2;
                }
            }
            __syncthreads();
        }
        if (tid == 0) {
            vals[k] = rv[0];
            inds[k] = ri[0];
            corrS[ri[0]] = -1e30f;
        }
        __syncthreads();
    }

    if (tid == 0) {
        float sum = 0.0f;
        for (int k = 0; k < KD; k++) sum += vals[k];
        const float inv = 1.0f / (sum + 1e-12f);
        for (int k = 0; k < KD; k++) {
            weights[bh * KD + k] = vals[k] * inv;
            delays[bh * KD + k]  = inds[k];
        }
    }
}

// weighted circular-shift gather
__global__ __launch_bounds__(256) void gather_ws(const float* __restrict__ v,
                                                 const int* __restrict__ delays,
                                                 const float* __restrict__ weights,
                                                 float* __restrict__ outb) {
    const int g  = blockIdx.x * 256 + threadIdx.x;
    const int c  = g & 511;
    const int bl = g >> 9;
    const int l  = bl & 2047;
    const int b  = bl >> 11;
    const int h  = c >> 6;
    const int dh = c & 63;
    const int bh = b * 8 + h;

    const float* vb = v + (size_t)bh * 131072;
    float acc = 0.0f;
#pragma unroll
    for (int k = 0; k < KD; k++) {
        const int   d = delays[bh * KD + k];
        const float w = weights[bh * KD + k];
        const int   p = (l + d) & 2047;
        acc = fmaf(w, vb[p * 64 + dh], acc);
    }
    outb[g] = acc;
}

extern "C" void kernel_launch(void* const* d_in, const int* in_sizes, int n_in,
                              void* d_out, int out_size, void* d_ws, size_t ws_size,
                              hipStream_t stream) {
    const float* x_q  = (const float*)d_in[0];
    const float* x_kv = (const float*)d_in[1];
    const float* Wq   = (const float*)d_in[2];
    const float* bq   = (const float*)d_in[3];
    const float* Wk   = (const float*)d_in[4];
    const float* bk   = (const float*)d_in[5];
    const float* Wv   = (const float*)d_in[6];
    const float* bv   = (const float*)d_in[7];
    const float* Wo   = (const float*)d_in[8];
    const float* bo   = (const float*)d_in[9];
    float* out = (float*)d_out;

    char* ws = (char*)d_ws;
    float* qbuf  = (float*)(ws + 0);            // [B,H,DH,L]; reused as gather out
    float* kbuf  = (float*)(ws + 33554432);
    float* vbuf  = (float*)(ws + 67108864);     // [B,H,L,DH] — written AFTER spec is dead
    float* spec  = (float*)(ws + 67108864);     // 1 MB, aliases vbuf (ordering-safe)
    int*   dely  = (int*)  (ws + 100663296);
    float* wgt   = (float*)(ws + 100665344);

    dim3 blk(256);
    dim3 gg(DD / 128, MM / 128);   // (4, 128)

    // q, k projections (split precision) into [B,H,DH,L]
    gemm_mfma<3><<<gg, blk, 0, stream>>>(x_q,  Wq, bq, qbuf, 1);
    gemm_mfma<3><<<gg, blk, 0, stream>>>(x_kv, Wk, bk, kbuf, 1);

    // full-2048-bin spectral accumulator (1 MB) must start at zero
    hipMemsetAsync(spec, 0, 64 * 2048 * 2 * sizeof(float), stream);

    fft_fwd<<<dim3(BB * HH * DHH), blk, 0, stream>>>(qbuf, kbuf, spec);
    fft_inv_topk<<<dim3(BB * HH), blk, 0, stream>>>(spec, dely, wgt);

    // v projection (plain fp16) into [B,H,L,DH] — overwrites spec region (now dead)
    gemm_mfma<1><<<gg, blk, 0, stream>>>(x_kv, Wv, bv, vbuf, 2);

    // weighted circular gather -> [B,L,D] (reuse qbuf)
    gather_ws<<<dim3(MM * DD / 256), blk, 0, stream>>>(vbuf, dely, wgt, qbuf);

    // final projection (plain fp16)
    gemm_mfma<1><<<gg, blk, 0, stream>>>(qbuf, Wo, bo, out, 0);
}

// Round 4
// 335.228 us; speedup vs baseline: 3.2842x; 3.2842x over previous
//
#include <hip/hip_runtime.h>
#include <math.h>

#define BB 8
#define LL 2048
#define DD 512
#define HH 8
#define DHH 64
#define KD 8
#define MM (BB*LL)   // 16384

typedef _Float16 f16x4 __attribute__((ext_vector_type(4)));
typedef _Float16 f16x8 __attribute__((ext_vector_type(8)));
typedef float    f32x4 __attribute__((ext_vector_type(4)));

// ---------------- MFMA GEMM: C = X @ W^T + bias ----------------
// NPROD==1: plain fp16. NPROD==3: hi/lo split for the score path.
template<int NPROD>
__global__ __launch_bounds__(256, 2) void gemm_mfma(const float* __restrict__ X,
                                                    const float* __restrict__ W,
                                                    const float* __restrict__ bias,
                                                    float* __restrict__ C,
                                                    int mode) {
    __shared__ __align__(16) _Float16 lds[(NPROD == 3) ? 20480 : 10240];
    _Float16* Ah = lds;
    _Float16* Bh = lds + 5120;
    _Float16* Al = (NPROD == 3) ? lds + 10240 : lds;
    _Float16* Bl = (NPROD == 3) ? lds + 15360 : lds;

    const int t    = threadIdx.x;
    const int m0   = blockIdx.y * 128;
    const int n0   = blockIdx.x * 128;
    const int srow = t >> 3;
    const int scol = (t & 7) * 4;
    const int wave = t >> 6;
    const int lane = t & 63;
    const int wm   = (wave >> 1) * 64;
    const int wn   = (wave & 1) * 64;
    const int lm   = lane & 15;
    const int quad = lane >> 4;

    f32x4 acc0[4][4] = {};
    f32x4 acc1[4][4] = {};

    float4 ar[4], br[4];
#pragma unroll
    for (int p = 0; p < 4; p++) {
        ar[p] = *(const float4*)(X + (size_t)(m0 + p * 32 + srow) * 512 + scol);
        br[p] = *(const float4*)(W + (size_t)(n0 + p * 32 + srow) * 512 + scol);
    }

    for (int k0 = 0; k0 < 512; k0 += 32) {
        __syncthreads();
#pragma unroll
        for (int p = 0; p < 4; p++) {
            const int row = p * 32 + srow;
            const float xa[4] = {ar[p].x, ar[p].y, ar[p].z, ar[p].w};
            const float xb[4] = {br[p].x, br[p].y, br[p].z, br[p].w};
            f16x4 ha, hb, la, lb;
#pragma unroll
            for (int j = 0; j < 4; j++) {
                const _Float16 h1 = (_Float16)xa[j];
                const _Float16 h2 = (_Float16)xb[j];
                ha[j] = h1; hb[j] = h2;
                if (NPROD == 3) {
                    la[j] = (_Float16)((xa[j] - (float)h1) * 512.0f);
                    lb[j] = (_Float16)((xb[j] - (float)h2) * 512.0f);
                }
            }
            *(f16x4*)&Ah[row * 40 + scol] = ha;
            *(f16x4*)&Bh[row * 40 + scol] = hb;
            if (NPROD == 3) {
                *(f16x4*)&Al[row * 40 + scol] = la;
                *(f16x4*)&Bl[row * 40 + scol] = lb;
            }
        }
        __syncthreads();

        if (k0 + 32 < 512) {
#pragma unroll
            for (int p = 0; p < 4; p++) {
                ar[p] = *(const float4*)(X + (size_t)(m0 + p * 32 + srow) * 512 + k0 + 32 + scol);
                br[p] = *(const float4*)(W + (size_t)(n0 + p * 32 + srow) * 512 + k0 + 32 + scol);
            }
        }

        f16x8 afh[4], bf[4];
#pragma unroll
        for (int mt = 0; mt < 4; mt++)
            afh[mt] = *(f16x8*)&Ah[(wm + mt * 16 + lm) * 40 + quad * 8];
#pragma unroll
        for (int nt = 0; nt < 4; nt++)
            bf[nt] = *(f16x8*)&Bh[(wn + nt * 16 + lm) * 40 + quad * 8];

#pragma unroll
        for (int mt = 0; mt < 4; mt++)
#pragma unroll
            for (int nt = 0; nt < 4; nt++)
                acc0[mt][nt] = __builtin_amdgcn_mfma_f32_16x16x32_f16(afh[mt], bf[nt], acc0[mt][nt], 0, 0, 0);

        if (NPROD == 3) {
            f16x8 afl[4];
#pragma unroll
            for (int mt = 0; mt < 4; mt++)
                afl[mt] = *(f16x8*)&Al[(wm + mt * 16 + lm) * 40 + quad * 8];
#pragma unroll
            for (int mt = 0; mt < 4; mt++)
#pragma unroll
                for (int nt = 0; nt < 4; nt++)
                    acc1[mt][nt] = __builtin_amdgcn_mfma_f32_16x16x32_f16(afl[mt], bf[nt], acc1[mt][nt], 0, 0, 0);
#pragma unroll
            for (int nt = 0; nt < 4; nt++)
                bf[nt] = *(f16x8*)&Bl[(wn + nt * 16 + lm) * 40 + quad * 8];
#pragma unroll
            for (int mt = 0; mt < 4; mt++)
#pragma unroll
                for (int nt = 0; nt < 4; nt++)
                    acc1[mt][nt] = __builtin_amdgcn_mfma_f32_16x16x32_f16(afh[mt], bf[nt], acc1[mt][nt], 0, 0, 0);
        }
    }

#pragma unroll
    for (int mt = 0; mt < 4; mt++) {
#pragma unroll
        for (int nt = 0; nt < 4; nt++) {
            const int n = n0 + wn + nt * 16 + lm;
            const float bv = bias[n];
#pragma unroll
            for (int r = 0; r < 4; r++) {
                const int m = m0 + wm + mt * 16 + quad * 4 + r;
                float val = acc0[mt][nt][r] + bv;
                if (NPROD == 3) val += acc1[mt][nt][r] * (1.0f / 512.0f);
                const int b_idx = m >> 11;
                const int l     = m & 2047;
                size_t addr;
                if (mode == 0)      addr = (size_t)m * 512 + n;
                else if (mode == 1) addr = ((size_t)(b_idx * 512 + n)) * 2048 + l;
                else                addr = (size_t)b_idx * 1048576 + (size_t)(n >> 6) * 131072
                                           + (size_t)l * 64 + (n & 63);
                C[addr] = val;
            }
        }
    }
}

// ============== register-resident radix-8 DIF forward FFT (N=2048) ==============
// Per block: 8 dh-sequences; products accumulated in LDS (bit-reversed position
// order = natural LDS indexing), one coalesced partial-spectrum store per block.
// NO atomics anywhere.
#define PADI(i) ((i) + ((((i) >> 5)) << 2))

__device__ inline float2 cmul2(float2 a, float2 w) {
    return make_float2(a.x * w.x - a.y * w.y, a.x * w.y + a.y * w.x);
}
__device__ inline float2 cadd2(float2 a, float2 b) { return make_float2(a.x + b.x, a.y + b.y); }
__device__ inline float2 csub2(float2 a, float2 b) { return make_float2(a.x - b.x, a.y - b.y); }

__global__ __launch_bounds__(256) void fft_fwd(const float* __restrict__ qT,
                                               const float* __restrict__ kT,
                                               float* __restrict__ specP) {
    const int blk = blockIdx.x;      // bh*8 + part
    const int bh   = blk >> 3;
    const int part = blk & 7;
    const int t    = threadIdx.x;
    __shared__ float2 Zs[2300];      // exchange buffer, PADI(2047)=2299
    __shared__ float2 Wt[1024];      // Wt[j] = exp(-2*pi*i*j/2048)
    __shared__ float2 Pacc[2048];    // product accumulator, bit-rev position order

#pragma unroll
    for (int s = 0; s < 4; s++) {
        const int j = t + s * 256;
        float sv, cv;
        __sincosf(2.0f * (float)M_PI * (float)j / 2048.0f, &sv, &cv);
        Wt[j] = make_float2(cv, -sv);
    }
#pragma unroll
    for (int s = 0; s < 8; s++) Pacc[t + 256 * s] = make_float2(0.0f, 0.0f);

    const int low5 = t & 31, hi3 = t >> 5;
    const int low2 = t & 3,  hi6 = t >> 2;

    for (int j8 = 0; j8 < 8; j8++) {
        const int seq = bh * 64 + part * 8 + j8;
        const float* qp = qT + (size_t)seq * 2048;
        const float* kp = kT + (size_t)seq * 2048;
        float2 z[8];
#pragma unroll
        for (int s = 0; s < 8; s++) z[s] = make_float2(qp[t + 256 * s], kp[t + 256 * s]);
        __syncthreads();   // Wt/Pacc ready (iter 0); Zs free (iter >0)

        // ---- round 1 (bits 10,9,8), jb = t ----
#pragma unroll
        for (int sp = 0; sp < 4; sp++) {
            float2 u = z[sp], v = z[sp + 4];
            z[sp]     = cadd2(u, v);
            z[sp + 4] = cmul2(csub2(u, v), Wt[t + 256 * sp]);
        }
#pragma unroll
        for (int base = 0; base < 8; base += 4)
#pragma unroll
            for (int q2 = 0; q2 < 2; q2++) {
                float2 u = z[base + q2], v = z[base + q2 + 2];
                z[base + q2]     = cadd2(u, v);
                z[base + q2 + 2] = cmul2(csub2(u, v), Wt[2 * (t + 256 * q2)]);
            }
        {
            const float2 w = Wt[4 * t];
#pragma unroll
            for (int e = 0; e < 8; e += 2) {
                float2 u = z[e], v = z[e + 1];
                z[e]     = cadd2(u, v);
                z[e + 1] = cmul2(csub2(u, v), w);
            }
        }

        // exchange 1
#pragma unroll
        for (int s = 0; s < 8; s++) Zs[PADI(t + 256 * s)] = z[s];
        __syncthreads();
#pragma unroll
        for (int s = 0; s < 8; s++) z[s] = Zs[PADI(low5 + 32 * s + 256 * hi3)];
        __syncthreads();

        // ---- round 2 (bits 7,6,5), jb = low5 ----
#pragma unroll
        for (int sp = 0; sp < 4; sp++) {
            float2 u = z[sp], v = z[sp + 4];
            z[sp]     = cadd2(u, v);
            z[sp + 4] = cmul2(csub2(u, v), Wt[8 * (low5 + 32 * sp)]);
        }
#pragma unroll
        for (int base = 0; base < 8; base += 4)
#pragma unroll
            for (int q2 = 0; q2 < 2; q2++) {
                float2 u = z[base + q2], v = z[base + q2 + 2];
                z[base + q2]     = cadd2(u, v);
                z[base + q2 + 2] = cmul2(csub2(u, v), Wt[16 * (low5 + 32 * q2)]);
            }
        {
            const float2 w = Wt[32 * low5];
#pragma unroll
            for (int e = 0; e < 8; e += 2) {
                float2 u = z[e], v = z[e + 1];
                z[e]     = cadd2(u, v);
                z[e + 1] = cmul2(csub2(u, v), w);
            }
        }

        // exchange 2
#pragma unroll
        for (int s = 0; s < 8; s++) Zs[PADI(low5 + 32 * s + 256 * hi3)] = z[s];
        __syncthreads();
#pragma unroll
        for (int s = 0; s < 8; s++) z[s] = Zs[PADI(low2 + 4 * s + 32 * hi6)];
        __syncthreads();

        // ---- round 3 (bits 4,3,2), jb = low2 ----
#pragma unroll
        for (int sp = 0; sp < 4; sp++) {
            float2 u = z[sp], v = z[sp + 4];
            z[sp]     = cadd2(u, v);
            z[sp + 4] = cmul2(csub2(u, v), Wt[64 * (low2 + 4 * sp)]);
        }
#pragma unroll
        for (int base = 0; base < 8; base += 4)
#pragma unroll
            for (int q2 = 0; q2 < 2; q2++) {
                float2 u = z[base + q2], v = z[base + q2 + 2];
                z[base + q2]     = cadd2(u, v);
                z[base + q2 + 2] = cmul2(csub2(u, v), Wt[128 * (low2 + 4 * q2)]);
            }
        {
            const float2 w = Wt[256 * low2];
#pragma unroll
            for (int e = 0; e < 8; e += 2) {
                float2 u = z[e], v = z[e + 1];
                z[e]     = cadd2(u, v);
                z[e + 1] = cmul2(csub2(u, v), w);
            }
        }

        // exchange 3
#pragma unroll
        for (int s = 0; s < 8; s++) Zs[PADI(low2 + 4 * s + 32 * hi6)] = z[s];
        __syncthreads();
#pragma unroll
        for (int s = 0; s < 8; s++) z[s] = Zs[PADI(8 * t + s)];
        __syncthreads();

        // ---- round 4 (bits 1,0) ----
#pragma unroll
        for (int base = 0; base < 8; base += 4) {
            {
                float2 u = z[base], v = z[base + 2];
                z[base]     = cadd2(u, v);
                z[base + 2] = csub2(u, v);
            }
            {
                float2 u = z[base + 1], v = z[base + 3];
                float2 d = csub2(u, v);
                z[base + 1] = cadd2(u, v);
                z[base + 3] = make_float2(d.y, -d.x);
            }
        }
#pragma unroll
        for (int e = 0; e < 8; e += 2) {
            float2 u = z[e], v = z[e + 1];
            z[e]     = cadd2(u, v);
            z[e + 1] = csub2(u, v);
        }

        // bit-rev-position store
#pragma unroll
        for (int s = 0; s < 8; s++) Zs[8 * t + s] = z[s];
        __syncthreads();

        // unpack q+ik; accumulate P at position p (freq f = rev11(p)) into LDS
#pragma unroll
        for (int s = 0; s < 8; s++) {
            const int p  = t + 256 * s;
            const int f  = (int)(__brev((unsigned)p) >> 21);
            const int fm = (2048 - f) & 2047;
            const int p2 = (int)(__brev((unsigned)fm) >> 21);
            const float2 zf = Zs[p];
            const float2 zm = Zs[p2];
            const float qr = 0.5f * (zf.x + zm.x);
            const float qi = 0.5f * (zf.y - zm.y);
            const float kr = 0.5f * (zf.y + zm.y);
            const float ki = 0.5f * (zm.x - zf.x);
            if (f != 0) {   // DC bin stays zero (mean subtraction)
                const float pr = qr * kr + qi * ki;
                const float pi = qi * kr - qr * ki;
                float2 acc = Pacc[p];
                Pacc[p] = make_float2(acc.x + pr, acc.y + pi);
            }
        }
        __syncthreads();   // Zs reads done before next iteration overwrites
    }

    // one coalesced partial-spectrum store (bit-rev position order)
    float2* outp = (float2*)specP + (size_t)blk * 2048;
#pragma unroll
    for (int s = 0; s < 8; s++) {
        const int p = t + 256 * s;
        outp[p] = Pacc[p];
    }
}

// ---------------- inverse twiddles ----------------
__device__ inline void build_twiddle(float2* Wt, int tid, float sign) {
#pragma unroll
    for (int s = 0; s < 4; s++) {
        const int j = tid + s * 256;
        const float a = 2.0f * (float)M_PI * (float)j / 2048.0f;
        float sv, cv;
        __sincosf(a, &sv, &cv);
        Wt[j] = make_float2(cv, sign * sv);
    }
}

// radix-2 stages WITHOUT bit-reversal: DIT, expects bit-reversed input order
__device__ inline void fft2048_stages(float2* Z, const float2* Wt, int tid) {
    for (int st = 0; st < 11; st++) {
        const int half = 1 << st;
        const int shift = 10 - st;
#pragma unroll
        for (int r = 0; r < 4; r++) {
            const int m   = tid + r * 256;
            const int grp = m >> st;
            const int pos = m & (half - 1);
            const int i0  = (grp << (st + 1)) + pos;
            const int i1  = i0 + half;
            const float2 w = Wt[pos << shift];
            const float2 a = Z[i0];
            const float2 b = Z[i1];
            const float tr = b.x * w.x - b.y * w.y;
            const float ti = b.x * w.y + b.y * w.x;
            Z[i0] = make_float2(a.x + tr, a.y + ti);
            Z[i1] = make_float2(a.x - tr, a.y - ti);
        }
        __syncthreads();
    }
}

// inverse + top-8: one block per (b,h); sums 8 partial spectra (bit-rev order)
__global__ __launch_bounds__(256) void fft_inv_topk(const float* __restrict__ specP,
                                                    int* __restrict__ delays,
                                                    float* __restrict__ weights) {
    const int bh  = blockIdx.x;
    const int tid = threadIdx.x;
    __shared__ float2 Z[2048];
    __shared__ float2 Wt[1024];
    __shared__ float  corrS[2048];
    __shared__ float  rv[256];
    __shared__ int    ri[256];
    __shared__ float  vals[KD];
    __shared__ int    inds[KD];

    build_twiddle(Wt, tid, +1.0f);

    const float2* sp = (const float2*)specP + (size_t)bh * 8 * 2048;
#pragma unroll
    for (int s = 0; s < 8; s++) {
        const int p = tid + s * 256;
        float2 acc = make_float2(0.0f, 0.0f);
#pragma unroll
        for (int part = 0; part < 8; part++) {
            const float2 v = sp[part * 2048 + p];
            acc.x += v.x; acc.y += v.y;
        }
        Z[p] = acc;
    }
    __syncthreads();
    fft2048_stages(Z, Wt, tid);

    const float scale = 1.0f / (2048.0f * 64.0f);
#pragma unroll
    for (int s = 0; s < 8; s++) {
        const int i = tid + s * 256;
        corrS[i] = Z[i].x * scale;
    }
    __syncthreads();

    for (int k = 0; k < KD; k++) {
        float best = -1e30f;
        int   bi   = 1 << 30;
        for (int i = tid; i < 2048; i += 256) {
            const float v = corrS[i];
            if (v > best || (v == best && i < bi)) { best = v; bi = i; }
        }
        rv[tid] = best;
        ri[tid] = bi;
        __syncthreads();
        for (int off = 128; off > 0; off >>= 1) {
            if (tid < off) {
                const float v2 = rv[tid + off];
                const int   i2 = ri[tid + off];
                if (v2 > rv[tid] || (v2 == rv[tid] && i2 < ri[tid])) {
                    rv[tid] = v2; ri[tid] = i2;
                }
            }
            __syncthreads();
        }
        if (tid == 0) {
            vals[k] = rv[0];
            inds[k] = ri[0];
            corrS[ri[0]] = -1e30f;
        }
        __syncthreads();
    }

    if (tid == 0) {
        float sum = 0.0f;
        for (int k = 0; k < KD; k++) sum += vals[k];
        const float inv = 1.0f / (sum + 1e-12f);
        for (int k = 0; k < KD; k++) {
            weights[bh * KD + k] = vals[k] * inv;
            delays[bh * KD + k]  = inds[k];
        }
    }
}

// weighted circular-shift gather
__global__ __launch_bounds__(256) void gather_ws(const float* __restrict__ v,
                                                 const int* __restrict__ delays,
                                                 const float* __restrict__ weights,
                                                 float* __restrict__ outb) {
    const int g  = blockIdx.x * 256 + threadIdx.x;
    const int c  = g & 511;
    const int bl = g >> 9;
    const int l  = bl & 2047;
    const int b  = bl >> 11;
    const int h  = c >> 6;
    const int dh = c & 63;
    const int bh = b * 8 + h;

    const float* vb = v + (size_t)bh * 131072;
    float acc = 0.0f;
#pragma unroll
    for (int k = 0; k < KD; k++) {
        const int   d = delays[bh * KD + k];
        const float w = weights[bh * KD + k];
        const int   p = (l + d) & 2047;
        acc = fmaf(w, vb[p * 64 + dh], acc);
    }
    outb[g] = acc;
}

extern "C" void kernel_launch(void* const* d_in, const int* in_sizes, int n_in,
                              void* d_out, int out_size, void* d_ws, size_t ws_size,
                              hipStream_t stream) {
    const float* x_q  = (const float*)d_in[0];
    const float* x_kv = (const float*)d_in[1];
    const float* Wq   = (const float*)d_in[2];
    const float* bq   = (const float*)d_in[3];
    const float* Wk   = (const float*)d_in[4];
    const float* bk   = (const float*)d_in[5];
    const float* Wv   = (const float*)d_in[6];
    const float* bv   = (const float*)d_in[7];
    const float* Wo   = (const float*)d_in[8];
    const float* bo   = (const float*)d_in[9];
    float* out = (float*)d_out;

    char* ws = (char*)d_ws;
    float* qbuf  = (float*)(ws + 0);            // [B,H,DH,L]; reused as gather out
    float* kbuf  = (float*)(ws + 33554432);
    float* vbuf  = (float*)(ws + 67108864);     // [B,H,L,DH] — written AFTER specP is dead
    float* specP = (float*)(ws + 67108864);     // 512 partial spectra × 16 KB = 8 MB, aliases vbuf
    int*   dely  = (int*)  (ws + 100663296);
    float* wgt   = (float*)(ws + 100665344);

    dim3 blk(256);
    dim3 gg(DD / 128, MM / 128);   // (4, 128)

    // q, k projections (split precision) into [B,H,DH,L]
    gemm_mfma<3><<<gg, blk, 0, stream>>>(x_q,  Wq, bq, qbuf, 1);
    gemm_mfma<3><<<gg, blk, 0, stream>>>(x_kv, Wk, bk, kbuf, 1);

    // forward FFTs: 512 blocks × 8 sequences, partial spectra, no atomics
    fft_fwd<<<dim3(512), blk, 0, stream>>>(qbuf, kbuf, specP);
    fft_inv_topk<<<dim3(BB * HH), blk, 0, stream>>>(specP, dely, wgt);

    // v projection (plain fp16) into [B,H,L,DH] — overwrites specP (now dead)
    gemm_mfma<1><<<gg, blk, 0, stream>>>(x_kv, Wv, bv, vbuf, 2);

    // weighted circular gather -> [B,L,D] (reuse qbuf)
    gather_ws<<<dim3(MM * DD / 256), blk, 0, stream>>>(vbuf, dely, wgt, qbuf);

    // final projection (plain fp16)
    gemm_mfma<1><<<gg, blk, 0, stream>>>(qbuf, Wo, bo, out, 0);
}

// Round 6
// 304.133 us; speedup vs baseline: 3.6200x; 1.1022x over previous
//
#include <hip/hip_runtime.h>
#include <math.h>

#define BB 8
#define LL 2048
#define DD 512
#define HH 8
#define DHH 64
#define KD 8
#define MM (BB*LL)   // 16384

typedef _Float16 f16x2 __attribute__((ext_vector_type(2)));
typedef _Float16 f16x4 __attribute__((ext_vector_type(4)));
typedef _Float16 f16x8 __attribute__((ext_vector_type(8)));
typedef float    f32x4 __attribute__((ext_vector_type(4)));

// ---------------- prep: fp32 -> fp16 hi/lo ----------------
__device__ inline void cvt8(const float* __restrict__ s, _Float16* hp, _Float16* lp) {
    const float4 a = *(const float4*)s;
    const float4 b = *(const float4*)(s + 4);
    const float v[8] = {a.x, a.y, a.z, a.w, b.x, b.y, b.z, b.w};
    f16x8 hi, lo;
#pragma unroll
    for (int j = 0; j < 8; j++) {
        const _Float16 h = (_Float16)v[j];
        hi[j] = h;
        lo[j] = (_Float16)((v[j] - (float)h) * 512.0f);
    }
    *(f16x8*)hp = hi;
    if (lp) *(f16x8*)lp = lo;
}

// x_q, x_kv -> hi/lo fp16 (8 elems/thread)
__global__ __launch_bounds__(256) void prep_x(const float* __restrict__ xq,
                                              const float* __restrict__ xkv,
                                              _Float16* __restrict__ Xq_h, _Float16* __restrict__ Xq_l,
                                              _Float16* __restrict__ Xkv_h, _Float16* __restrict__ Xkv_l) {
    const int g = blockIdx.x * 256 + threadIdx.x;      // 2097152 threads
    const int which = g >> 20;
    const size_t idx = (size_t)(g & 1048575) * 8;
    const float* src = which ? xkv : xq;
    _Float16* dh = which ? Xkv_h : Xq_h;
    _Float16* dl = which ? Xkv_l : Xq_l;
    cvt8(src + idx, dh + idx, dl + idx);
}

// Wq,Wk -> hi/lo; Wv,Wo -> hi only
__global__ __launch_bounds__(256) void prep_w(const float* __restrict__ Wq, const float* __restrict__ Wk,
                                              const float* __restrict__ Wv, const float* __restrict__ Wo,
                                              _Float16* __restrict__ Wq_h, _Float16* __restrict__ Wq_l,
                                              _Float16* __restrict__ Wk_h, _Float16* __restrict__ Wk_l,
                                              _Float16* __restrict__ Wv_h, _Float16* __restrict__ Wo_h) {
    const int g = blockIdx.x * 256 + threadIdx.x;      // 131072 threads
    const int which = g >> 15;
    const size_t idx = (size_t)(g & 32767) * 8;
    if (which == 0)      cvt8(Wq + idx, Wq_h + idx, Wq_l + idx);
    else if (which == 1) cvt8(Wk + idx, Wk_h + idx, Wk_l + idx);
    else if (which == 2) cvt8(Wv + idx, Wv_h + idx, nullptr);
    else                 cvt8(Wo + idx, Wo_h + idx, nullptr);
}

// ---------------- MFMA GEMM on pre-converted fp16: C = A @ B^T + bias ----------------
// NPROD==1: plain (hi only). NPROD==3: hi/lo split (score path).
// MODE 0: fp32 C[m*512+n]
// MODE 1: fp32 C[(b*512+n)*2048+l]   <-- score path STAYS fp32 in storage
// MODE 2: fp16 v-layout C[b,h,l,dh]
template<int NPROD, int MODE>
__global__ __launch_bounds__(256, 2) void gemm_f16(const _Float16* __restrict__ Ag,
                                                   const _Float16* __restrict__ Al_g,
                                                   const _Float16* __restrict__ Bg,
                                                   const _Float16* __restrict__ Bl_g,
                                                   const float* __restrict__ bias,
                                                   void* __restrict__ Cv) {
    __shared__ __align__(16) _Float16 lds[(NPROD == 3) ? 20480 : 10240];
    _Float16* Ah = lds;            // [128][40] halves
    _Float16* Bh = lds + 5120;
    _Float16* Al = (NPROD == 3) ? lds + 10240 : lds;
    _Float16* Bl = (NPROD == 3) ? lds + 15360 : lds;

    const int t  = threadIdx.x;
    const int l0 = blockIdx.x;                  // XCD-aware swizzle (xcd = id%8)
    const int m0 = (((l0 >> 5) << 3) | (l0 & 7)) * 128;
    const int n0 = ((l0 >> 3) & 3) * 128;

    const int lrow = t >> 2;        // 0..63
    const int lcol = (t & 3) * 8;   // 0,8,16,24
    const int wave = t >> 6;
    const int lane = t & 63;
    const int wm   = (wave >> 1) * 64;
    const int wn   = (wave & 1) * 64;
    const int lm   = lane & 15;
    const int quad = lane >> 4;

    f32x4 acc0[4][4] = {};
    f32x4 acc1[4][4] = {};

    f16x8 pa[2], pb[2], pal[2], pbl[2];
#pragma unroll
    for (int p = 0; p < 2; p++) {
        pa[p] = *(const f16x8*)(Ag + (size_t)(m0 + p * 64 + lrow) * 512 + lcol);
        pb[p] = *(const f16x8*)(Bg + (size_t)(n0 + p * 64 + lrow) * 512 + lcol);
        if (NPROD == 3) {
            pal[p] = *(const f16x8*)(Al_g + (size_t)(m0 + p * 64 + lrow) * 512 + lcol);
            pbl[p] = *(const f16x8*)(Bl_g + (size_t)(n0 + p * 64 + lrow) * 512 + lcol);
        }
    }

    for (int k0 = 0; k0 < 512; k0 += 32) {
        __syncthreads();
#pragma unroll
        for (int p = 0; p < 2; p++) {
            const int row = p * 64 + lrow;
            *(f16x8*)&Ah[row * 40 + lcol] = pa[p];
            *(f16x8*)&Bh[row * 40 + lcol] = pb[p];
            if (NPROD == 3) {
                *(f16x8*)&Al[row * 40 + lcol] = pal[p];
                *(f16x8*)&Bl[row * 40 + lcol] = pbl[p];
            }
        }
        __syncthreads();

        if (k0 + 32 < 512) {
            const int kn = k0 + 32;
#pragma unroll
            for (int p = 0; p < 2; p++) {
                pa[p] = *(const f16x8*)(Ag + (size_t)(m0 + p * 64 + lrow) * 512 + kn + lcol);
                pb[p] = *(const f16x8*)(Bg + (size_t)(n0 + p * 64 + lrow) * 512 + kn + lcol);
                if (NPROD == 3) {
                    pal[p] = *(const f16x8*)(Al_g + (size_t)(m0 + p * 64 + lrow) * 512 + kn + lcol);
                    pbl[p] = *(const f16x8*)(Bl_g + (size_t)(n0 + p * 64 + lrow) * 512 + kn + lcol);
                }
            }
        }

        f16x8 afh[4], bf[4];
#pragma unroll
        for (int mt = 0; mt < 4; mt++)
            afh[mt] = *(f16x8*)&Ah[(wm + mt * 16 + lm) * 40 + quad * 8];
#pragma unroll
        for (int nt = 0; nt < 4; nt++)
            bf[nt] = *(f16x8*)&Bh[(wn + nt * 16 + lm) * 40 + quad * 8];

#pragma unroll
        for (int mt = 0; mt < 4; mt++)
#pragma unroll
            for (int nt = 0; nt < 4; nt++)
                acc0[mt][nt] = __builtin_amdgcn_mfma_f32_16x16x32_f16(afh[mt], bf[nt], acc0[mt][nt], 0, 0, 0);

        if (NPROD == 3) {
            f16x8 afl[4];
#pragma unroll
            for (int mt = 0; mt < 4; mt++)
                afl[mt] = *(f16x8*)&Al[(wm + mt * 16 + lm) * 40 + quad * 8];
#pragma unroll
            for (int mt = 0; mt < 4; mt++)
#pragma unroll
                for (int nt = 0; nt < 4; nt++)
                    acc1[mt][nt] = __builtin_amdgcn_mfma_f32_16x16x32_f16(afl[mt], bf[nt], acc1[mt][nt], 0, 0, 0);
#pragma unroll
            for (int nt = 0; nt < 4; nt++)
                bf[nt] = *(f16x8*)&Bl[(wn + nt * 16 + lm) * 40 + quad * 8];
#pragma unroll
            for (int mt = 0; mt < 4; mt++)
#pragma unroll
                for (int nt = 0; nt < 4; nt++)
                    acc1[mt][nt] = __builtin_amdgcn_mfma_f32_16x16x32_f16(afh[mt], bf[nt], acc1[mt][nt], 0, 0, 0);
        }
    }

    // epilogue: C/D layout col=lane&15, row=quad*4+reg
#pragma unroll
    for (int mt = 0; mt < 4; mt++) {
#pragma unroll
        for (int nt = 0; nt < 4; nt++) {
            const int n = n0 + wn + nt * 16 + lm;
            const float bv = bias[n];
            float val[4];
#pragma unroll
            for (int r = 0; r < 4; r++) {
                val[r] = acc0[mt][nt][r] + bv;
                if (NPROD == 3) val[r] += acc1[mt][nt][r] * (1.0f / 512.0f);
            }
            const int mbase = m0 + wm + mt * 16 + quad * 4;   // multiple of 4
            const int b_idx = mbase >> 11;
            const int lbase = mbase & 2047;
            if (MODE == 0) {
                float* C = (float*)Cv;
#pragma unroll
                for (int r = 0; r < 4; r++) C[(size_t)(mbase + r) * 512 + n] = val[r];
            } else if (MODE == 1) {
                float* C = (float*)Cv;
                float4 pv = make_float4(val[0], val[1], val[2], val[3]);
                *(float4*)&C[((size_t)(b_idx * 512 + n)) * 2048 + lbase] = pv;
            } else {
                _Float16* C = (_Float16*)Cv;
#pragma unroll
                for (int r = 0; r < 4; r++)
                    C[(size_t)b_idx * 1048576 + (size_t)(n >> 6) * 131072
                      + (size_t)(lbase + r) * 64 + (n & 63)] = (_Float16)val[r];
            }
        }
    }
}

// ============== register-resident radix-8 DIF forward FFT (N=2048), fp32 in ==============
#define PADI(i) ((i) + ((((i) >> 5)) << 2))

__device__ inline float2 cmul2(float2 a, float2 w) {
    return make_float2(a.x * w.x - a.y * w.y, a.x * w.y + a.y * w.x);
}
__device__ inline float2 cadd2(float2 a, float2 b) { return make_float2(a.x + b.x, a.y + b.y); }
__device__ inline float2 csub2(float2 a, float2 b) { return make_float2(a.x - b.x, a.y - b.y); }

__global__ __launch_bounds__(256) void fft_fwd(const float* __restrict__ qT,
                                               const float* __restrict__ kT,
                                               float* __restrict__ specP) {
    const int blk = blockIdx.x;      // bh*8 + part
    const int bh   = blk >> 3;
    const int part = blk & 7;
    const int t    = threadIdx.x;
    __shared__ float2 Zs[2300];
    __shared__ float2 Wt[1024];
    __shared__ float2 Pacc[2048];

#pragma unroll
    for (int s = 0; s < 4; s++) {
        const int j = t + s * 256;
        float sv, cv;
        __sincosf(2.0f * (float)M_PI * (float)j / 2048.0f, &sv, &cv);
        Wt[j] = make_float2(cv, -sv);
    }
#pragma unroll
    for (int s = 0; s < 8; s++) Pacc[t + 256 * s] = make_float2(0.0f, 0.0f);

    const int low5 = t & 31, hi3 = t >> 5;
    const int low2 = t & 3,  hi6 = t >> 2;

    for (int j8 = 0; j8 < 8; j8++) {
        const int seq = bh * 64 + part * 8 + j8;
        const float* qp = qT + (size_t)seq * 2048;
        const float* kp = kT + (size_t)seq * 2048;
        float2 z[8];
#pragma unroll
        for (int s = 0; s < 8; s++) z[s] = make_float2(qp[t + 256 * s], kp[t + 256 * s]);
        __syncthreads();

        // round 1 (bits 10,9,8)
#pragma unroll
        for (int sp = 0; sp < 4; sp++) {
            float2 u = z[sp], v = z[sp + 4];
            z[sp]     = cadd2(u, v);
            z[sp + 4] = cmul2(csub2(u, v), Wt[t + 256 * sp]);
        }
#pragma unroll
        for (int base = 0; base < 8; base += 4)
#pragma unroll
            for (int q2 = 0; q2 < 2; q2++) {
                float2 u = z[base + q2], v = z[base + q2 + 2];
                z[base + q2]     = cadd2(u, v);
                z[base + q2 + 2] = cmul2(csub2(u, v), Wt[2 * (t + 256 * q2)]);
            }
        {
            const float2 w = Wt[4 * t];
#pragma unroll
            for (int e = 0; e < 8; e += 2) {
                float2 u = z[e], v = z[e + 1];
                z[e]     = cadd2(u, v);
                z[e + 1] = cmul2(csub2(u, v), w);
            }
        }

#pragma unroll
        for (int s = 0; s < 8; s++) Zs[PADI(t + 256 * s)] = z[s];
        __syncthreads();
#pragma unroll
        for (int s = 0; s < 8; s++) z[s] = Zs[PADI(low5 + 32 * s + 256 * hi3)];
        __syncthreads();

        // round 2 (bits 7,6,5)
#pragma unroll
        for (int sp = 0; sp < 4; sp++) {
            float2 u = z[sp], v = z[sp + 4];
            z[sp]     = cadd2(u, v);
            z[sp + 4] = cmul2(csub2(u, v), Wt[8 * (low5 + 32 * sp)]);
        }
#pragma unroll
        for (int base = 0; base < 8; base += 4)
#pragma unroll
            for (int q2 = 0; q2 < 2; q2++) {
                float2 u = z[base + q2], v = z[base + q2 + 2];
                z[base + q2]     = cadd2(u, v);
                z[base + q2 + 2] = cmul2(csub2(u, v), Wt[16 * (low5 + 32 * q2)]);
            }
        {
            const float2 w = Wt[32 * low5];
#pragma unroll
            for (int e = 0; e < 8; e += 2) {
                float2 u = z[e], v = z[e + 1];
                z[e]     = cadd2(u, v);
                z[e + 1] = cmul2(csub2(u, v), w);
            }
        }

#pragma unroll
        for (int s = 0; s < 8; s++) Zs[PADI(low5 + 32 * s + 256 * hi3)] = z[s];
        __syncthreads();
#pragma unroll
        for (int s = 0; s < 8; s++) z[s] = Zs[PADI(low2 + 4 * s + 32 * hi6)];
        __syncthreads();

        // round 3 (bits 4,3,2)
#pragma unroll
        for (int sp = 0; sp < 4; sp++) {
            float2 u = z[sp], v = z[sp + 4];
            z[sp]     = cadd2(u, v);
            z[sp + 4] = cmul2(csub2(u, v), Wt[64 * (low2 + 4 * sp)]);
        }
#pragma unroll
        for (int base = 0; base < 8; base += 4)
#pragma unroll
            for (int q2 = 0; q2 < 2; q2++) {
                float2 u = z[base + q2], v = z[base + q2 + 2];
                z[base + q2]     = cadd2(u, v);
                z[base + q2 + 2] = cmul2(csub2(u, v), Wt[128 * (low2 + 4 * q2)]);
            }
        {
            const float2 w = Wt[256 * low2];
#pragma unroll
            for (int e = 0; e < 8; e += 2) {
                float2 u = z[e], v = z[e + 1];
                z[e]     = cadd2(u, v);
                z[e + 1] = cmul2(csub2(u, v), w);
            }
        }

#pragma unroll
        for (int s = 0; s < 8; s++) Zs[PADI(low2 + 4 * s + 32 * hi6)] = z[s];
        __syncthreads();
#pragma unroll
        for (int s = 0; s < 8; s++) z[s] = Zs[PADI(8 * t + s)];
        __syncthreads();

        // round 4 (bits 1,0)
#pragma unroll
        for (int base = 0; base < 8; base += 4) {
            {
                float2 u = z[base], v = z[base + 2];
                z[base]     = cadd2(u, v);
                z[base + 2] = csub2(u, v);
            }
            {
                float2 u = z[base + 1], v = z[base + 3];
                float2 d = csub2(u, v);
                z[base + 1] = cadd2(u, v);
                z[base + 3] = make_float2(d.y, -d.x);
            }
        }
#pragma unroll
        for (int e = 0; e < 8; e += 2) {
            float2 u = z[e], v = z[e + 1];
            z[e]     = cadd2(u, v);
            z[e + 1] = csub2(u, v);
        }

#pragma unroll
        for (int s = 0; s < 8; s++) Zs[8 * t + s] = z[s];
        __syncthreads();

#pragma unroll
        for (int s = 0; s < 8; s++) {
            const int p  = t + 256 * s;
            const int f  = (int)(__brev((unsigned)p) >> 21);
            const int fm = (2048 - f) & 2047;
            const int p2 = (int)(__brev((unsigned)fm) >> 21);
            const float2 zf = Zs[p];
            const float2 zm = Zs[p2];
            const float qr = 0.5f * (zf.x + zm.x);
            const float qi = 0.5f * (zf.y - zm.y);
            const float kr = 0.5f * (zf.y + zm.y);
            const float ki = 0.5f * (zm.x - zf.x);
            if (f != 0) {
                const float pr = qr * kr + qi * ki;
                const float pi = qi * kr - qr * ki;
                float2 acc = Pacc[p];
                Pacc[p] = make_float2(acc.x + pr, acc.y + pi);
            }
        }
        __syncthreads();
    }

    float2* outp = (float2*)specP + (size_t)blk * 2048;
#pragma unroll
    for (int s = 0; s < 8; s++) {
        const int p = t + 256 * s;
        outp[p] = Pacc[p];
    }
}

// ---------------- inverse (DIT over bit-reversed input) + top-8 ----------------
__device__ inline void build_twiddle(float2* Wt, int tid, float sign) {
#pragma unroll
    for (int s = 0; s < 4; s++) {
        const int j = tid + s * 256;
        const float a = 2.0f * (float)M_PI * (float)j / 2048.0f;
        float sv, cv;
        __sincosf(a, &sv, &cv);
        Wt[j] = make_float2(cv, sign * sv);
    }
}

__device__ inline void fft2048_stages(float2* Z, const float2* Wt, int tid) {
    for (int st = 0; st < 11; st++) {
        const int half = 1 << st;
        const int shift = 10 - st;
#pragma unroll
        for (int r = 0; r < 4; r++) {
            const int m   = tid + r * 256;
            const int grp = m >> st;
            const int pos = m & (half - 1);
            const int i0  = (grp << (st + 1)) + pos;
            const int i1  = i0 + half;
            const float2 w = Wt[pos << shift];
            const float2 a = Z[i0];
            const float2 b = Z[i1];
            const float tr = b.x * w.x - b.y * w.y;
            const float ti = b.x * w.y + b.y * w.x;
            Z[i0] = make_float2(a.x + tr, a.y + ti);
            Z[i1] = make_float2(a.x - tr, a.y - ti);
        }
        __syncthreads();
    }
}

__global__ __launch_bounds__(256) void fft_inv_topk(const float* __restrict__ specP,
                                                    int* __restrict__ delays,
                                                    float* __restrict__ weights) {
    const int bh  = blockIdx.x;
    const int tid = threadIdx.x;
    __shared__ float2 Z[2048];
    __shared__ float2 Wt[1024];
    __shared__ float  corrS[2048];
    __shared__ float  rv[256];
    __shared__ int    ri[256];
    __shared__ float  vals[KD];
    __shared__ int    inds[KD];

    build_twiddle(Wt, tid, +1.0f);

    const float2* sp = (const float2*)specP + (size_t)bh * 8 * 2048;
#pragma unroll
    for (int s = 0; s < 8; s++) {
        const int p = tid + s * 256;
        float2 acc = make_float2(0.0f, 0.0f);
#pragma unroll
        for (int part = 0; part < 8; part++) {
            const float2 v = sp[part * 2048 + p];
            acc.x += v.x; acc.y += v.y;
        }
        Z[p] = acc;
    }
    __syncthreads();
    fft2048_stages(Z, Wt, tid);

    const float scale = 1.0f / (2048.0f * 64.0f);
#pragma unroll
    for (int s = 0; s < 8; s++) {
        const int i = tid + s * 256;
        corrS[i] = Z[i].x * scale;
    }
    __syncthreads();

    for (int k = 0; k < KD; k++) {
        float best = -1e30f;
        int   bi   = 1 << 30;
        for (int i = tid; i < 2048; i += 256) {
            const float v = corrS[i];
            if (v > best || (v == best && i < bi)) { best = v; bi = i; }
        }
        rv[tid] = best;
        ri[tid] = bi;
        __syncthreads();
        for (int off = 128; off > 0; off >>= 1) {
            if (tid < off) {
                const float v2 = rv[tid + off];
                const int   i2 = ri[tid + off];
                if (v2 > rv[tid] || (v2 == rv[tid] && i2 < ri[tid])) {
                    rv[tid] = v2; ri[tid] = i2;
                }
            }
            __syncthreads();
        }
        if (tid == 0) {
            vals[k] = rv[0];
            inds[k] = ri[0];
            corrS[ri[0]] = -1e30f;
        }
        __syncthreads();
    }

    if (tid == 0) {
        float sum = 0.0f;
        for (int k = 0; k < KD; k++) sum += vals[k];
        const float inv = 1.0f / (sum + 1e-12f);
        for (int k = 0; k < KD; k++) {
            weights[bh * KD + k] = vals[k] * inv;
            delays[bh * KD + k]  = inds[k];
        }
    }
}

// weighted circular-shift gather, fp16 in/out, 2 dh per thread
__global__ __launch_bounds__(256) void gather_ws(const _Float16* __restrict__ v,
                                                 const int* __restrict__ delays,
                                                 const float* __restrict__ weights,
                                                 _Float16* __restrict__ outb) {
    const int gp  = blockIdx.x * 256 + threadIdx.x;   // pair index over M*256
    const int ch2 = gp & 255;
    const int m   = gp >> 8;
    const int l   = m & 2047;
    const int b   = m >> 11;
    const int ch  = ch2 * 2;
    const int h   = ch >> 6;
    const int dh  = ch & 63;
    const int bh  = b * 8 + h;

    const _Float16* vb = v + (size_t)bh * 131072;
    float a0 = 0.0f, a1 = 0.0f;
#pragma unroll
    for (int k = 0; k < KD; k++) {
        const int   d = delays[bh * KD + k];
        const float w = weights[bh * KD + k];
        const int   p = (l + d) & 2047;
        const f16x2 pv = *(const f16x2*)&vb[p * 64 + dh];
        a0 = fmaf(w, (float)pv[0], a0);
        a1 = fmaf(w, (float)pv[1], a1);
    }
    f16x2 ov;
    ov[0] = (_Float16)a0;
    ov[1] = (_Float16)a1;
    *(f16x2*)&outb[(size_t)m * 512 + ch] = ov;
}

extern "C" void kernel_launch(void* const* d_in, const int* in_sizes, int n_in,
                              void* d_out, int out_size, void* d_ws, size_t ws_size,
                              hipStream_t stream) {
    const float* x_q  = (const float*)d_in[0];
    const float* x_kv = (const float*)d_in[1];
    const float* Wq   = (const float*)d_in[2];
    const float* bq   = (const float*)d_in[3];
    const float* Wk   = (const float*)d_in[4];
    const float* bk   = (const float*)d_in[5];
    const float* Wv   = (const float*)d_in[6];
    const float* bv   = (const float*)d_in[7];
    const float* Wo   = (const float*)d_in[8];
    const float* bo   = (const float*)d_in[9];
    float* out = (float*)d_out;

    // ---- workspace choreography (stream-ordered aliasing; peak 70.3 MB) ----
    char* ws = (char*)d_ws;
    _Float16* Xq_h  = (_Float16*)(ws + 0);           // 16 MiB (dead after q-gemm)
    _Float16* Xq_l  = (_Float16*)(ws + 16777216);    // 16 MiB (dead after q-gemm)
    _Float16* Xkv_h = (_Float16*)(ws + 33554432);    // 16 MiB (live until v-gemm)
    _Float16* Xkv_l = (_Float16*)(ws + 50331648);    // 16 MiB (dead after k-gemm)
    _Float16* Wq_h  = (_Float16*)(ws + 67108864);
    _Float16* Wq_l  = (_Float16*)(ws + 67633152);
    _Float16* Wk_h  = (_Float16*)(ws + 68157440);
    _Float16* Wk_l  = (_Float16*)(ws + 68681728);
    _Float16* Wv_h  = (_Float16*)(ws + 69206016);
    _Float16* Wo_h  = (_Float16*)(ws + 69730304);
    int*      dely  = (int*)    (ws + 70254592);
    float*    wgt   = (float*)  (ws + 70256640);
    // aliases (each written only after the region underneath is dead):
    float*    kf32  = (float*)  (ws + 0);            // 32 MiB over Xq_h+Xq_l (k-gemm runs after q-gemm)
    float*    specP = (float*)  (ws + 50331648);     // 8 MB over Xkv_l (fft_fwd runs after k-gemm)
    _Float16* vh    = (_Float16*)(ws + 0);           // 16 MiB over kf32 (v-gemm after fft_fwd)
    _Float16* gbuf  = (_Float16*)(ws + 16777216);    // 16 MiB over kf32 upper half
    // q fp32 [B,H,DH,L] lives in d_out (33.55 MB, fully rewritten by final GEMM)
    float*    qf32  = (float*)d_out;

    dim3 blk(256);

    prep_x<<<dim3(8192), blk, 0, stream>>>(x_q, x_kv, Xq_h, Xq_l, Xkv_h, Xkv_l);
    prep_w<<<dim3(512),  blk, 0, stream>>>(Wq, Wk, Wv, Wo, Wq_h, Wq_l, Wk_h, Wk_l, Wv_h, Wo_h);

    // q projection (hi/lo) -> fp32 [B,H,DH,L] in d_out
    gemm_f16<3, 1><<<dim3(512), blk, 0, stream>>>(Xq_h,  Xq_l,  Wq_h, Wq_l, bq, qf32);
    // k projection (hi/lo) -> fp32, overwrites dead Xq region
    gemm_f16<3, 1><<<dim3(512), blk, 0, stream>>>(Xkv_h, Xkv_l, Wk_h, Wk_l, bk, kf32);

    // forward FFTs -> partial spectra (no atomics), over dead Xkv_l
    fft_fwd<<<dim3(512), blk, 0, stream>>>(qf32, kf32, specP);
    fft_inv_topk<<<dim3(BB * HH), blk, 0, stream>>>(specP, dely, wgt);

    // v projection (plain fp16) -> fp16 [B,H,L,DH], over dead kf32 low half
    gemm_f16<1, 2><<<dim3(512), blk, 0, stream>>>(Xkv_h, Xkv_h, Wv_h, Wv_h, bv, vh);

    // weighted circular gather -> fp16 [B,L,D], over dead kf32 high half
    gather_ws<<<dim3(MM * 256 / 256), blk, 0, stream>>>(vh, dely, wgt, gbuf);

    // final projection -> fp32 output (d_out; qf32 dead)
    gemm_f16<1, 0><<<dim3(512), blk, 0, stream>>>(gbuf, gbuf, Wo_h, Wo_h, bo, out);
}

// Round 7
// 301.034 us; speedup vs baseline: 3.6573x; 1.0103x over previous
//
#include <hip/hip_runtime.h>
#include <math.h>

#define BB 8
#define LL 2048
#define DD 512
#define HH 8
#define DHH 64
#define KD 8
#define MM (BB*LL)   // 16384

typedef _Float16 f16x2 __attribute__((ext_vector_type(2)));
typedef _Float16 f16x4 __attribute__((ext_vector_type(4)));
typedef _Float16 f16x8 __attribute__((ext_vector_type(8)));
typedef float    f32x4 __attribute__((ext_vector_type(4)));

// ---------------- prep: fp32 -> fp16 hi/lo (x and W fused in one launch) ----------------
__device__ inline void cvt8(const float* __restrict__ s, _Float16* hp, _Float16* lp) {
    const float4 a = *(const float4*)s;
    const float4 b = *(const float4*)(s + 4);
    const float v[8] = {a.x, a.y, a.z, a.w, b.x, b.y, b.z, b.w};
    f16x8 hi, lo;
#pragma unroll
    for (int j = 0; j < 8; j++) {
        const _Float16 h = (_Float16)v[j];
        hi[j] = h;
        lo[j] = (_Float16)((v[j] - (float)h) * 512.0f);
    }
    *(f16x8*)hp = hi;
    if (lp) *(f16x8*)lp = lo;
}

__global__ __launch_bounds__(256) void prep_all(const float* __restrict__ xq,
                                                const float* __restrict__ xkv,
                                                const float* __restrict__ Wq, const float* __restrict__ Wk,
                                                const float* __restrict__ Wv, const float* __restrict__ Wo,
                                                _Float16* __restrict__ Xq_h, _Float16* __restrict__ Xq_l,
                                                _Float16* __restrict__ Xkv_h, _Float16* __restrict__ Xkv_l,
                                                _Float16* __restrict__ Wq_h, _Float16* __restrict__ Wq_l,
                                                _Float16* __restrict__ Wk_h, _Float16* __restrict__ Wk_l,
                                                _Float16* __restrict__ Wv_h, _Float16* __restrict__ Wo_h) {
    const int bid = blockIdx.x;
    if (bid < 8192) {   // x_q / x_kv: 2097152 threads × 8 elems
        const int g = bid * 256 + threadIdx.x;
        const int which = g >> 20;
        const size_t idx = (size_t)(g & 1048575) * 8;
        const float* src = which ? xkv : xq;
        _Float16* dh = which ? Xkv_h : Xq_h;
        _Float16* dl = which ? Xkv_l : Xq_l;
        cvt8(src + idx, dh + idx, dl + idx);
    } else {            // weights: 131072 threads × 8 elems
        const int g = (bid - 8192) * 256 + threadIdx.x;
        const int which = g >> 15;
        const size_t idx = (size_t)(g & 32767) * 8;
        if (which == 0)      cvt8(Wq + idx, Wq_h + idx, Wq_l + idx);
        else if (which == 1) cvt8(Wk + idx, Wk_h + idx, Wk_l + idx);
        else if (which == 2) cvt8(Wv + idx, Wv_h + idx, nullptr);
        else                 cvt8(Wo + idx, Wo_h + idx, nullptr);
    }
}

// ---------------- MFMA GEMM on pre-converted fp16: C = A @ B^T + bias ----------------
// NPROD==1: plain (hi only). NPROD==3: hi/lo split (score path).
// MODE 0: fp32 C[m*512+n]
// MODE 1: fp32 C[(b*512+n)*2048+l]   (score path stays fp32 in storage)
// MODE 2: fp16 v-layout C[b,h,l,dh]
template<int NPROD, int MODE>
__global__ __launch_bounds__(256, 2) void gemm_f16(const _Float16* __restrict__ Ag,
                                                   const _Float16* __restrict__ Al_g,
                                                   const _Float16* __restrict__ Bg,
                                                   const _Float16* __restrict__ Bl_g,
                                                   const float* __restrict__ bias,
                                                   void* __restrict__ Cv) {
    __shared__ __align__(16) _Float16 lds[(NPROD == 3) ? 20480 : 10240];
    _Float16* Ah = lds;            // [128][40] halves
    _Float16* Bh = lds + 5120;
    _Float16* Al = (NPROD == 3) ? lds + 10240 : lds;
    _Float16* Bl = (NPROD == 3) ? lds + 15360 : lds;

    const int t  = threadIdx.x;
    const int l0 = blockIdx.x;                  // XCD-aware swizzle (xcd = id%8)
    const int m0 = (((l0 >> 5) << 3) | (l0 & 7)) * 128;
    const int n0 = ((l0 >> 3) & 3) * 128;

    const int lrow = t >> 2;        // 0..63
    const int lcol = (t & 3) * 8;   // 0,8,16,24
    const int wave = t >> 6;
    const int lane = t & 63;
    const int wm   = (wave >> 1) * 64;
    const int wn   = (wave & 1) * 64;
    const int lm   = lane & 15;
    const int quad = lane >> 4;

    f32x4 acc0[4][4] = {};
    f32x4 acc1[4][4] = {};

    f16x8 pa[2], pb[2], pal[2], pbl[2];
#pragma unroll
    for (int p = 0; p < 2; p++) {
        pa[p] = *(const f16x8*)(Ag + (size_t)(m0 + p * 64 + lrow) * 512 + lcol);
        pb[p] = *(const f16x8*)(Bg + (size_t)(n0 + p * 64 + lrow) * 512 + lcol);
        if (NPROD == 3) {
            pal[p] = *(const f16x8*)(Al_g + (size_t)(m0 + p * 64 + lrow) * 512 + lcol);
            pbl[p] = *(const f16x8*)(Bl_g + (size_t)(n0 + p * 64 + lrow) * 512 + lcol);
        }
    }

    for (int k0 = 0; k0 < 512; k0 += 32) {
        __syncthreads();
#pragma unroll
        for (int p = 0; p < 2; p++) {
            const int row = p * 64 + lrow;
            *(f16x8*)&Ah[row * 40 + lcol] = pa[p];
            *(f16x8*)&Bh[row * 40 + lcol] = pb[p];
            if (NPROD == 3) {
                *(f16x8*)&Al[row * 40 + lcol] = pal[p];
                *(f16x8*)&Bl[row * 40 + lcol] = pbl[p];
            }
        }
        __syncthreads();

        if (k0 + 32 < 512) {
            const int kn = k0 + 32;
#pragma unroll
            for (int p = 0; p < 2; p++) {
                pa[p] = *(const f16x8*)(Ag + (size_t)(m0 + p * 64 + lrow) * 512 + kn + lcol);
                pb[p] = *(const f16x8*)(Bg + (size_t)(n0 + p * 64 + lrow) * 512 + kn + lcol);
                if (NPROD == 3) {
                    pal[p] = *(const f16x8*)(Al_g + (size_t)(m0 + p * 64 + lrow) * 512 + kn + lcol);
                    pbl[p] = *(const f16x8*)(Bl_g + (size_t)(n0 + p * 64 + lrow) * 512 + kn + lcol);
                }
            }
        }

        f16x8 afh[4], bf[4];
#pragma unroll
        for (int mt = 0; mt < 4; mt++)
            afh[mt] = *(f16x8*)&Ah[(wm + mt * 16 + lm) * 40 + quad * 8];
#pragma unroll
        for (int nt = 0; nt < 4; nt++)
            bf[nt] = *(f16x8*)&Bh[(wn + nt * 16 + lm) * 40 + quad * 8];

#pragma unroll
        for (int mt = 0; mt < 4; mt++)
#pragma unroll
            for (int nt = 0; nt < 4; nt++)
                acc0[mt][nt] = __builtin_amdgcn_mfma_f32_16x16x32_f16(afh[mt], bf[nt], acc0[mt][nt], 0, 0, 0);

        if (NPROD == 3) {
            f16x8 afl[4];
#pragma unroll
            for (int mt = 0; mt < 4; mt++)
                afl[mt] = *(f16x8*)&Al[(wm + mt * 16 + lm) * 40 + quad * 8];
#pragma unroll
            for (int mt = 0; mt < 4; mt++)
#pragma unroll
                for (int nt = 0; nt < 4; nt++)
                    acc1[mt][nt] = __builtin_amdgcn_mfma_f32_16x16x32_f16(afl[mt], bf[nt], acc1[mt][nt], 0, 0, 0);
#pragma unroll
            for (int nt = 0; nt < 4; nt++)
                bf[nt] = *(f16x8*)&Bl[(wn + nt * 16 + lm) * 40 + quad * 8];
#pragma unroll
            for (int mt = 0; mt < 4; mt++)
#pragma unroll
                for (int nt = 0; nt < 4; nt++)
                    acc1[mt][nt] = __builtin_amdgcn_mfma_f32_16x16x32_f16(afh[mt], bf[nt], acc1[mt][nt], 0, 0, 0);
        }
    }

    // epilogue: C/D layout col=lane&15, row=quad*4+reg
#pragma unroll
    for (int mt = 0; mt < 4; mt++) {
#pragma unroll
        for (int nt = 0; nt < 4; nt++) {
            const int n = n0 + wn + nt * 16 + lm;
            const float bv = bias[n];
            float val[4];
#pragma unroll
            for (int r = 0; r < 4; r++) {
                val[r] = acc0[mt][nt][r] + bv;
                if (NPROD == 3) val[r] += acc1[mt][nt][r] * (1.0f / 512.0f);
            }
            const int mbase = m0 + wm + mt * 16 + quad * 4;   // multiple of 4
            const int b_idx = mbase >> 11;
            const int lbase = mbase & 2047;
            if (MODE == 0) {
                float* C = (float*)Cv;
#pragma unroll
                for (int r = 0; r < 4; r++) C[(size_t)(mbase + r) * 512 + n] = val[r];
            } else if (MODE == 1) {
                float* C = (float*)Cv;
                float4 pv = make_float4(val[0], val[1], val[2], val[3]);
                *(float4*)&C[((size_t)(b_idx * 512 + n)) * 2048 + lbase] = pv;
            } else {
                _Float16* C = (_Float16*)Cv;
#pragma unroll
                for (int r = 0; r < 4; r++)
                    C[(size_t)b_idx * 1048576 + (size_t)(n >> 6) * 131072
                      + (size_t)(lbase + r) * 64 + (n & 63)] = (_Float16)val[r];
            }
        }
    }
}

// ============== register-resident radix-8 DIF forward FFT (N=2048), fp32 in ==============
// 1024 blocks × 4 sequences. Product accumulator in REGISTERS (positions fixed
// per thread). PAD3 pad keeps every exchange pattern at the b64 bank floor.
#define PAD3(i) ((i) + ((i) >> 3))

__device__ inline float2 cmul2(float2 a, float2 w) {
    return make_float2(a.x * w.x - a.y * w.y, a.x * w.y + a.y * w.x);
}
__device__ inline float2 cadd2(float2 a, float2 b) { return make_float2(a.x + b.x, a.y + b.y); }
__device__ inline float2 csub2(float2 a, float2 b) { return make_float2(a.x - b.x, a.y - b.y); }

__global__ __launch_bounds__(256) void fft_fwd(const float* __restrict__ qT,
                                               const float* __restrict__ kT,
                                               float* __restrict__ specP) {
    const int blk  = blockIdx.x;     // bh*16 + part
    const int bh   = blk >> 4;
    const int part = blk & 15;
    const int t    = threadIdx.x;
    __shared__ float2 Zs[2304];      // PAD3(2047) = 2302
    __shared__ float2 Wt[1024];      // Wt[j] = exp(-2*pi*i*j/2048)

#pragma unroll
    for (int s = 0; s < 4; s++) {
        const int j = t + s * 256;
        float sv, cv;
        __sincosf(2.0f * (float)M_PI * (float)j / 2048.0f, &sv, &cv);
        Wt[j] = make_float2(cv, -sv);
    }

    float2 pacc[8];
#pragma unroll
    for (int s = 0; s < 8; s++) pacc[s] = make_float2(0.0f, 0.0f);

    const int low5 = t & 31, hi3 = t >> 5;
    const int low2 = t & 3,  hi6 = t >> 2;

    for (int j4 = 0; j4 < 4; j4++) {
        const int seq = bh * 64 + part * 4 + j4;
        const float* qp = qT + (size_t)seq * 2048;
        const float* kp = kT + (size_t)seq * 2048;
        float2 z[8];
#pragma unroll
        for (int s = 0; s < 8; s++) z[s] = make_float2(qp[t + 256 * s], kp[t + 256 * s]);
        __syncthreads();   // Wt ready (iter 0); prev unpack reads done (iter >0)

        // ---- round 1 (bits 10,9,8), jb = t ----
#pragma unroll
        for (int sp = 0; sp < 4; sp++) {
            float2 u = z[sp], v = z[sp + 4];
            z[sp]     = cadd2(u, v);
            z[sp + 4] = cmul2(csub2(u, v), Wt[t + 256 * sp]);
        }
#pragma unroll
        for (int base = 0; base < 8; base += 4)
#pragma unroll
            for (int q2 = 0; q2 < 2; q2++) {
                float2 u = z[base + q2], v = z[base + q2 + 2];
                z[base + q2]     = cadd2(u, v);
                z[base + q2 + 2] = cmul2(csub2(u, v), Wt[2 * (t + 256 * q2)]);
            }
        {
            const float2 w = Wt[4 * t];
#pragma unroll
            for (int e = 0; e < 8; e += 2) {
                float2 u = z[e], v = z[e + 1];
                z[e]     = cadd2(u, v);
                z[e + 1] = cmul2(csub2(u, v), w);
            }
        }

        // exchange 1: (t+256s) -> (low5+32s+256hi3)
#pragma unroll
        for (int s = 0; s < 8; s++) Zs[PAD3(t + 256 * s)] = z[s];
        __syncthreads();
#pragma unroll
        for (int s = 0; s < 8; s++) z[s] = Zs[PAD3(low5 + 32 * s + 256 * hi3)];
        // no barrier: round-2 writes go back to the SAME slots this thread just read

        // ---- round 2 (bits 7,6,5), jb = low5 ----
#pragma unroll
        for (int sp = 0; sp < 4; sp++) {
            float2 u = z[sp], v = z[sp + 4];
            z[sp]     = cadd2(u, v);
            z[sp + 4] = cmul2(csub2(u, v), Wt[8 * (low5 + 32 * sp)]);
        }
#pragma unroll
        for (int base = 0; base < 8; base += 4)
#pragma unroll
            for (int q2 = 0; q2 < 2; q2++) {
                float2 u = z[base + q2], v = z[base + q2 + 2];
                z[base + q2]     = cadd2(u, v);
                z[base + q2 + 2] = cmul2(csub2(u, v), Wt[16 * (low5 + 32 * q2)]);
            }
        {
            const float2 w = Wt[32 * low5];
#pragma unroll
            for (int e = 0; e < 8; e += 2) {
                float2 u = z[e], v = z[e + 1];
                z[e]     = cadd2(u, v);
                z[e + 1] = cmul2(csub2(u, v), w);
            }
        }

        // exchange 2: (low5+32s+256hi3) -> (low2+4s+32hi6)
#pragma unroll
        for (int s = 0; s < 8; s++) Zs[PAD3(low5 + 32 * s + 256 * hi3)] = z[s];
        __syncthreads();
#pragma unroll
        for (int s = 0; s < 8; s++) z[s] = Zs[PAD3(low2 + 4 * s + 32 * hi6)];

        // ---- round 3 (bits 4,3,2), jb = low2 ----
#pragma unroll
        for (int sp = 0; sp < 4; sp++) {
            float2 u = z[sp], v = z[sp + 4];
            z[sp]     = cadd2(u, v);
            z[sp + 4] = cmul2(csub2(u, v), Wt[64 * (low2 + 4 * sp)]);
        }
#pragma unroll
        for (int base = 0; base < 8; base += 4)
#pragma unroll
            for (int q2 = 0; q2 < 2; q2++) {
                float2 u = z[base + q2], v = z[base + q2 + 2];
                z[base + q2]     = cadd2(u, v);
                z[base + q2 + 2] = cmul2(csub2(u, v), Wt[128 * (low2 + 4 * q2)]);
            }
        {
            const float2 w = Wt[256 * low2];
#pragma unroll
            for (int e = 0; e < 8; e += 2) {
                float2 u = z[e], v = z[e + 1];
                z[e]     = cadd2(u, v);
                z[e + 1] = cmul2(csub2(u, v), w);
            }
        }

        // exchange 3: (low2+4s+32hi6) -> (8t+s)
#pragma unroll
        for (int s = 0; s < 8; s++) Zs[PAD3(low2 + 4 * s + 32 * hi6)] = z[s];
        __syncthreads();
#pragma unroll
        for (int s = 0; s < 8; s++) z[s] = Zs[PAD3(8 * t + s)];

        // ---- round 4 (bits 1,0) ----
#pragma unroll
        for (int base = 0; base < 8; base += 4) {
            {
                float2 u = z[base], v = z[base + 2];
                z[base]     = cadd2(u, v);
                z[base + 2] = csub2(u, v);
            }
            {
                float2 u = z[base + 1], v = z[base + 3];
                float2 d = csub2(u, v);
                z[base + 1] = cadd2(u, v);
                z[base + 3] = make_float2(d.y, -d.x);
            }
        }
#pragma unroll
        for (int e = 0; e < 8; e += 2) {
            float2 u = z[e], v = z[e + 1];
            z[e]     = cadd2(u, v);
            z[e + 1] = csub2(u, v);
        }

        // write back completed FFT (same slots this thread read -> only one barrier)
#pragma unroll
        for (int s = 0; s < 8; s++) Zs[PAD3(8 * t + s)] = z[s];
        __syncthreads();

        // unpack q+ik; accumulate P at thread-fixed positions p = t+256s (registers)
#pragma unroll
        for (int s = 0; s < 8; s++) {
            const int p  = t + 256 * s;
            const int f  = (int)(__brev((unsigned)p) >> 21);
            const int fm = (2048 - f) & 2047;
            const int p2 = (int)(__brev((unsigned)fm) >> 21);
            const float2 zf = Zs[PAD3(p)];
            const float2 zm = Zs[PAD3(p2)];
            const float qr = 0.5f * (zf.x + zm.x);
            const float qi = 0.5f * (zf.y - zm.y);
            const float kr = 0.5f * (zf.y + zm.y);
            const float ki = 0.5f * (zm.x - zf.x);
            if (f != 0) {   // DC bin stays zero (mean subtraction)
                pacc[s].x += qr * kr + qi * ki;
                pacc[s].y += qi * kr - qr * ki;
            }
        }
    }

    // one coalesced partial-spectrum store (bit-rev position order)
    float2* outp = (float2*)specP + (size_t)blk * 2048;
#pragma unroll
    for (int s = 0; s < 8; s++) outp[t + 256 * s] = pacc[s];
}

// ---------------- inverse (DIT over bit-reversed input) + top-8 ----------------
__device__ inline void build_twiddle(float2* Wt, int tid, float sign) {
#pragma unroll
    for (int s = 0; s < 4; s++) {
        const int j = tid + s * 256;
        const float a = 2.0f * (float)M_PI * (float)j / 2048.0f;
        float sv, cv;
        __sincosf(a, &sv, &cv);
        Wt[j] = make_float2(cv, sign * sv);
    }
}

__device__ inline void fft2048_stages(float2* Z, const float2* Wt, int tid) {
    for (int st = 0; st < 11; st++) {
        const int half = 1 << st;
        const int shift = 10 - st;
#pragma unroll
        for (int r = 0; r < 4; r++) {
            const int m   = tid + r * 256;
            const int grp = m >> st;
            const int pos = m & (half - 1);
            const int i0  = (grp << (st + 1)) + pos;
            const int i1  = i0 + half;
            const float2 w = Wt[pos << shift];
            const float2 a = Z[i0];
            const float2 b = Z[i1];
            const float tr = b.x * w.x - b.y * w.y;
            const float ti = b.x * w.y + b.y * w.x;
            Z[i0] = make_float2(a.x + tr, a.y + ti);
            Z[i1] = make_float2(a.x - tr, a.y - ti);
        }
        __syncthreads();
    }
}

__global__ __launch_bounds__(256) void fft_inv_topk(const float* __restrict__ specP,
                                                    int* __restrict__ delays,
                                                    float* __restrict__ weights) {
    const int bh  = blockIdx.x;
    const int tid = threadIdx.x;
    __shared__ float2 Z[2048];
    __shared__ float2 Wt[1024];
    __shared__ float  corrS[2048];
    __shared__ float  rv[256];
    __shared__ int    ri[256];
    __shared__ float  vals[KD];
    __shared__ int    inds[KD];

    build_twiddle(Wt, tid, +1.0f);

    const float2* sp = (const float2*)specP + (size_t)bh * 16 * 2048;
#pragma unroll
    for (int s = 0; s < 8; s++) {
        const int p = tid + s * 256;
        float2 acc = make_float2(0.0f, 0.0f);
#pragma unroll
        for (int part = 0; part < 16; part++) {
            const float2 v = sp[part * 2048 + p];
            acc.x += v.x; acc.y += v.y;
        }
        Z[p] = acc;
    }
    __syncthreads();
    fft2048_stages(Z, Wt, tid);

    const float scale = 1.0f / (2048.0f * 64.0f);
#pragma unroll
    for (int s = 0; s < 8; s++) {
        const int i = tid + s * 256;
        corrS[i] = Z[i].x * scale;
    }
    __syncthreads();

    for (int k = 0; k < KD; k++) {
        float best = -1e30f;
        int   bi   = 1 << 30;
        for (int i = tid; i < 2048; i += 256) {
            const float v = corrS[i];
            if (v > best || (v == best && i < bi)) { best = v; bi = i; }
        }
        rv[tid] = best;
        ri[tid] = bi;
        __syncthreads();
        for (int off = 128; off > 0; off >>= 1) {
            if (tid < off) {
                const float v2 = rv[tid + off];
                const int   i2 = ri[tid + off];
                if (v2 > rv[tid] || (v2 == rv[tid] && i2 < ri[tid])) {
                    rv[tid] = v2; ri[tid] = i2;
                }
            }
            __syncthreads();
        }
        if (tid == 0) {
            vals[k] = rv[0];
            inds[k] = ri[0];
            corrS[ri[0]] = -1e30f;
        }
        __syncthreads();
    }

    if (tid == 0) {
        float sum = 0.0f;
        for (int k = 0; k < KD; k++) sum += vals[k];
        const float inv = 1.0f / (sum + 1e-12f);
        for (int k = 0; k < KD; k++) {
            weights[bh * KD + k] = vals[k] * inv;
            delays[bh * KD + k]  = inds[k];
        }
    }
}

// weighted circular-shift gather, fp16 in/out, 4 dh per thread
__global__ __launch_bounds__(256) void gather_ws(const _Float16* __restrict__ v,
                                                 const int* __restrict__ delays,
                                                 const float* __restrict__ weights,
                                                 _Float16* __restrict__ outb) {
    const int gp = blockIdx.x * 256 + threadIdx.x;   // over M*128 = 2097152
    const int c4 = gp & 127;
    const int m  = gp >> 7;
    const int l  = m & 2047;
    const int b  = m >> 11;
    const int ch = c4 * 4;
    const int h  = ch >> 6;
    const int dh = ch & 63;
    const int bh = b * 8 + h;

    const _Float16* vb = v + (size_t)bh * 131072;
    float a0 = 0.0f, a1 = 0.0f, a2 = 0.0f, a3 = 0.0f;
#pragma unroll
    for (int k = 0; k < KD; k++) {
        const int   d = delays[bh * KD + k];
        const float w = weights[bh * KD + k];
        const int   p = (l + d) & 2047;
        const f16x4 pv = *(const f16x4*)&vb[p * 64 + dh];
        a0 = fmaf(w, (float)pv[0], a0);
        a1 = fmaf(w, (float)pv[1], a1);
        a2 = fmaf(w, (float)pv[2], a2);
        a3 = fmaf(w, (float)pv[3], a3);
    }
    f16x4 ov;
    ov[0] = (_Float16)a0;
    ov[1] = (_Float16)a1;
    ov[2] = (_Float16)a2;
    ov[3] = (_Float16)a3;
    *(f16x4*)&outb[(size_t)m * 512 + ch] = ov;
}

extern "C" void kernel_launch(void* const* d_in, const int* in_sizes, int n_in,
                              void* d_out, int out_size, void* d_ws, size_t ws_size,
                              hipStream_t stream) {
    const float* x_q  = (const float*)d_in[0];
    const float* x_kv = (const float*)d_in[1];
    const float* Wq   = (const float*)d_in[2];
    const float* bq   = (const float*)d_in[3];
    const float* Wk   = (const float*)d_in[4];
    const float* bk   = (const float*)d_in[5];
    const float* Wv   = (const float*)d_in[6];
    const float* bv   = (const float*)d_in[7];
    const float* Wo   = (const float*)d_in[8];
    const float* bo   = (const float*)d_in[9];
    float* out = (float*)d_out;

    // ---- workspace choreography (stream-ordered aliasing; peak 70.3 MB) ----
    char* ws = (char*)d_ws;
    _Float16* Xq_h  = (_Float16*)(ws + 0);           // 16 MiB (dead after q-gemm)
    _Float16* Xq_l  = (_Float16*)(ws + 16777216);    // 16 MiB (dead after q-gemm)
    _Float16* Xkv_h = (_Float16*)(ws + 33554432);    // 16 MiB (live until v-gemm)
    _Float16* Xkv_l = (_Float16*)(ws + 50331648);    // 16 MiB (dead after k-gemm)
    _Float16* Wq_h  = (_Float16*)(ws + 67108864);
    _Float16* Wq_l  = (_Float16*)(ws + 67633152);
    _Float16* Wk_h  = (_Float16*)(ws + 68157440);
    _Float16* Wk_l  = (_Float16*)(ws + 68681728);
    _Float16* Wv_h  = (_Float16*)(ws + 69206016);
    _Float16* Wo_h  = (_Float16*)(ws + 69730304);
    int*      dely  = (int*)    (ws + 70254592);
    float*    wgt   = (float*)  (ws + 70256640);
    // aliases (each written only after the region underneath is dead):
    float*    kf32  = (float*)  (ws + 0);            // 32 MiB over Xq_h+Xq_l
    float*    specP = (float*)  (ws + 50331648);     // 16 MiB over Xkv_l (1024 partials)
    _Float16* vh    = (_Float16*)(ws + 0);           // 16 MiB over kf32 low half
    _Float16* gbuf  = (_Float16*)(ws + 16777216);    // 16 MiB over kf32 high half
    // q fp32 [B,H,DH,L] lives in d_out (33.55 MB, fully rewritten by final GEMM)
    float*    qf32  = (float*)d_out;

    dim3 blk(256);

    prep_all<<<dim3(8704), blk, 0, stream>>>(x_q, x_kv, Wq, Wk, Wv, Wo,
                                             Xq_h, Xq_l, Xkv_h, Xkv_l,
                                             Wq_h, Wq_l, Wk_h, Wk_l, Wv_h, Wo_h);

    // q projection (hi/lo) -> fp32 [B,H,DH,L] in d_out
    gemm_f16<3, 1><<<dim3(512), blk, 0, stream>>>(Xq_h,  Xq_l,  Wq_h, Wq_l, bq, qf32);
    // k projection (hi/lo) -> fp32, overwrites dead Xq region
    gemm_f16<3, 1><<<dim3(512), blk, 0, stream>>>(Xkv_h, Xkv_l, Wk_h, Wk_l, bk, kf32);

    // forward FFTs: 1024 blocks × 4 sequences -> 16 partials/bh (no atomics)
    fft_fwd<<<dim3(1024), blk, 0, stream>>>(qf32, kf32, specP);
    fft_inv_topk<<<dim3(BB * HH), blk, 0, stream>>>(specP, dely, wgt);

    // v projection (plain fp16) -> fp16 [B,H,L,DH], over dead kf32 low half
    gemm_f16<1, 2><<<dim3(512), blk, 0, stream>>>(Xkv_h, Xkv_h, Wv_h, Wv_h, bv, vh);

    // weighted circular gather -> fp16 [B,L,D], over dead kf32 high half
    gather_ws<<<dim3(8192), blk, 0, stream>>>(vh, dely, wgt, gbuf);

    // final projection -> fp32 output (d_out; qf32 dead)
    gemm_f16<1, 0><<<dim3(512), blk, 0, stream>>>(gbuf, gbuf, Wo_h, Wo_h, bo, out);
}

// Round 8
// 294.823 us; speedup vs baseline: 3.7343x; 1.0211x over previous
//
#include <hip/hip_runtime.h>
#include <math.h>

#define BB 8
#define LL 2048
#define DD 512
#define HH 8
#define DHH 64
#define KD 8
#define MM (BB*LL)   // 16384

typedef _Float16 f16x2 __attribute__((ext_vector_type(2)));
typedef _Float16 f16x4 __attribute__((ext_vector_type(4)));
typedef _Float16 f16x8 __attribute__((ext_vector_type(8)));
typedef float    f32x4 __attribute__((ext_vector_type(4)));

// ---------------- prep: fp32 -> fp16 hi/lo (x and W fused in one launch) ----------------
__device__ inline void cvt8(const float* __restrict__ s, _Float16* hp, _Float16* lp) {
    const float4 a = *(const float4*)s;
    const float4 b = *(const float4*)(s + 4);
    const float v[8] = {a.x, a.y, a.z, a.w, b.x, b.y, b.z, b.w};
    f16x8 hi, lo;
#pragma unroll
    for (int j = 0; j < 8; j++) {
        const _Float16 h = (_Float16)v[j];
        hi[j] = h;
        lo[j] = (_Float16)((v[j] - (float)h) * 512.0f);
    }
    *(f16x8*)hp = hi;
    if (lp) *(f16x8*)lp = lo;
}

__global__ __launch_bounds__(256) void prep_all(const float* __restrict__ xq,
                                                const float* __restrict__ xkv,
                                                const float* __restrict__ Wq, const float* __restrict__ Wk,
                                                const float* __restrict__ Wv, const float* __restrict__ Wo,
                                                _Float16* __restrict__ Xq_h, _Float16* __restrict__ Xq_l,
                                                _Float16* __restrict__ Xkv_h, _Float16* __restrict__ Xkv_l,
                                                _Float16* __restrict__ Wq_h, _Float16* __restrict__ Wq_l,
                                                _Float16* __restrict__ Wk_h, _Float16* __restrict__ Wk_l,
                                                _Float16* __restrict__ Wv_h, _Float16* __restrict__ Wo_h) {
    const int bid = blockIdx.x;
    if (bid < 8192) {   // x_q / x_kv: 2097152 threads × 8 elems
        const int g = bid * 256 + threadIdx.x;
        const int which = g >> 20;
        const size_t idx = (size_t)(g & 1048575) * 8;
        const float* src = which ? xkv : xq;
        _Float16* dh = which ? Xkv_h : Xq_h;
        _Float16* dl = which ? Xkv_l : Xq_l;
        cvt8(src + idx, dh + idx, dl + idx);
    } else {            // weights: 131072 threads × 8 elems
        const int g = (bid - 8192) * 256 + threadIdx.x;
        const int which = g >> 15;
        const size_t idx = (size_t)(g & 32767) * 8;
        if (which == 0)      cvt8(Wq + idx, Wq_h + idx, Wq_l + idx);
        else if (which == 1) cvt8(Wk + idx, Wk_h + idx, Wk_l + idx);
        else if (which == 2) cvt8(Wv + idx, Wv_h + idx, nullptr);
        else                 cvt8(Wo + idx, Wo_h + idx, nullptr);
    }
}

// ---------------- MFMA GEMM body (device fn): C = A @ B^T + bias ----------------
// NPROD==1: plain (hi only). NPROD==3: hi/lo split (score path).
// MODE 0: fp32 C[m*512+n]
// MODE 1: fp32 C[(b*512+n)*2048+l]   (score path stays fp32 in storage)
// MODE 2: fp16 v-layout C[b,h,l,dh]
template<int NPROD, int MODE>
__device__ __forceinline__ void gemm_body(const _Float16* __restrict__ Ag,
                                          const _Float16* __restrict__ Al_g,
                                          const _Float16* __restrict__ Bg,
                                          const _Float16* __restrict__ Bl_g,
                                          const float* __restrict__ bias,
                                          void* __restrict__ Cv,
                                          _Float16* lds, int l0) {
    _Float16* Ah = lds;            // [128][40] halves
    _Float16* Bh = lds + 5120;
    _Float16* Al = (NPROD == 3) ? lds + 10240 : lds;
    _Float16* Bl = (NPROD == 3) ? lds + 15360 : lds;

    const int t  = threadIdx.x;
    const int m0 = (((l0 >> 5) << 3) | (l0 & 7)) * 128;   // XCD-aware swizzle (xcd = id%8)
    const int n0 = ((l0 >> 3) & 3) * 128;

    const int lrow = t >> 2;        // 0..63
    const int lcol = (t & 3) * 8;   // 0,8,16,24
    const int wave = t >> 6;
    const int lane = t & 63;
    const int wm   = (wave >> 1) * 64;
    const int wn   = (wave & 1) * 64;
    const int lm   = lane & 15;
    const int quad = lane >> 4;

    f32x4 acc0[4][4] = {};
    f32x4 acc1[4][4] = {};

    f16x8 pa[2], pb[2], pal[2], pbl[2];
#pragma unroll
    for (int p = 0; p < 2; p++) {
        pa[p] = *(const f16x8*)(Ag + (size_t)(m0 + p * 64 + lrow) * 512 + lcol);
        pb[p] = *(const f16x8*)(Bg + (size_t)(n0 + p * 64 + lrow) * 512 + lcol);
        if (NPROD == 3) {
            pal[p] = *(const f16x8*)(Al_g + (size_t)(m0 + p * 64 + lrow) * 512 + lcol);
            pbl[p] = *(const f16x8*)(Bl_g + (size_t)(n0 + p * 64 + lrow) * 512 + lcol);
        }
    }

    for (int k0 = 0; k0 < 512; k0 += 32) {
        __syncthreads();
#pragma unroll
        for (int p = 0; p < 2; p++) {
            const int row = p * 64 + lrow;
            *(f16x8*)&Ah[row * 40 + lcol] = pa[p];
            *(f16x8*)&Bh[row * 40 + lcol] = pb[p];
            if (NPROD == 3) {
                *(f16x8*)&Al[row * 40 + lcol] = pal[p];
                *(f16x8*)&Bl[row * 40 + lcol] = pbl[p];
            }
        }
        __syncthreads();

        if (k0 + 32 < 512) {
            const int kn = k0 + 32;
#pragma unroll
            for (int p = 0; p < 2; p++) {
                pa[p] = *(const f16x8*)(Ag + (size_t)(m0 + p * 64 + lrow) * 512 + kn + lcol);
                pb[p] = *(const f16x8*)(Bg + (size_t)(n0 + p * 64 + lrow) * 512 + kn + lcol);
                if (NPROD == 3) {
                    pal[p] = *(const f16x8*)(Al_g + (size_t)(m0 + p * 64 + lrow) * 512 + kn + lcol);
                    pbl[p] = *(const f16x8*)(Bl_g + (size_t)(n0 + p * 64 + lrow) * 512 + kn + lcol);
                }
            }
        }

        f16x8 afh[4], bf[4];
#pragma unroll
        for (int mt = 0; mt < 4; mt++)
            afh[mt] = *(f16x8*)&Ah[(wm + mt * 16 + lm) * 40 + quad * 8];
#pragma unroll
        for (int nt = 0; nt < 4; nt++)
            bf[nt] = *(f16x8*)&Bh[(wn + nt * 16 + lm) * 40 + quad * 8];

#pragma unroll
        for (int mt = 0; mt < 4; mt++)
#pragma unroll
            for (int nt = 0; nt < 4; nt++)
                acc0[mt][nt] = __builtin_amdgcn_mfma_f32_16x16x32_f16(afh[mt], bf[nt], acc0[mt][nt], 0, 0, 0);

        if (NPROD == 3) {
            f16x8 afl[4];
#pragma unroll
            for (int mt = 0; mt < 4; mt++)
                afl[mt] = *(f16x8*)&Al[(wm + mt * 16 + lm) * 40 + quad * 8];
#pragma unroll
            for (int mt = 0; mt < 4; mt++)
#pragma unroll
                for (int nt = 0; nt < 4; nt++)
                    acc1[mt][nt] = __builtin_amdgcn_mfma_f32_16x16x32_f16(afl[mt], bf[nt], acc1[mt][nt], 0, 0, 0);
#pragma unroll
            for (int nt = 0; nt < 4; nt++)
                bf[nt] = *(f16x8*)&Bl[(wn + nt * 16 + lm) * 40 + quad * 8];
#pragma unroll
            for (int mt = 0; mt < 4; mt++)
#pragma unroll
                for (int nt = 0; nt < 4; nt++)
                    acc1[mt][nt] = __builtin_amdgcn_mfma_f32_16x16x32_f16(afh[mt], bf[nt], acc1[mt][nt], 0, 0, 0);
        }
    }

    // epilogue: C/D layout col=lane&15, row=quad*4+reg
#pragma unroll
    for (int mt = 0; mt < 4; mt++) {
#pragma unroll
        for (int nt = 0; nt < 4; nt++) {
            const int n = n0 + wn + nt * 16 + lm;
            const float bv = bias[n];
            float val[4];
#pragma unroll
            for (int r = 0; r < 4; r++) {
                val[r] = acc0[mt][nt][r] + bv;
                if (NPROD == 3) val[r] += acc1[mt][nt][r] * (1.0f / 512.0f);
            }
            const int mbase = m0 + wm + mt * 16 + quad * 4;   // multiple of 4
            const int b_idx = mbase >> 11;
            const int lbase = mbase & 2047;
            if (MODE == 0) {
                float* C = (float*)Cv;
#pragma unroll
                for (int r = 0; r < 4; r++) C[(size_t)(mbase + r) * 512 + n] = val[r];
            } else if (MODE == 1) {
                float* C = (float*)Cv;
                float4 pv = make_float4(val[0], val[1], val[2], val[3]);
                *(float4*)&C[((size_t)(b_idx * 512 + n)) * 2048 + lbase] = pv;
            } else {
                _Float16* C = (_Float16*)Cv;
#pragma unroll
                for (int r = 0; r < 4; r++)
                    C[(size_t)b_idx * 1048576 + (size_t)(n >> 6) * 131072
                      + (size_t)(lbase + r) * 64 + (n & 63)] = (_Float16)val[r];
            }
        }
    }
}

// merged q+k projection: 1024 blocks; blocks 0-511 = q, 512-1023 = k
__global__ __launch_bounds__(256, 2) void gemm_qk(const _Float16* __restrict__ A0h, const _Float16* __restrict__ A0l,
                                                  const _Float16* __restrict__ B0h, const _Float16* __restrict__ B0l,
                                                  const float* __restrict__ bias0, float* __restrict__ C0,
                                                  const _Float16* __restrict__ A1h, const _Float16* __restrict__ A1l,
                                                  const _Float16* __restrict__ B1h, const _Float16* __restrict__ B1l,
                                                  const float* __restrict__ bias1, float* __restrict__ C1) {
    __shared__ __align__(16) _Float16 lds[20480];
    const int prob = blockIdx.x >> 9;
    const int l0   = blockIdx.x & 511;
    if (prob == 0)
        gemm_body<3, 1>(A0h, A0l, B0h, B0l, bias0, C0, lds, l0);
    else
        gemm_body<3, 1>(A1h, A1l, B1h, B1l, bias1, C1, lds, l0);
}

__global__ __launch_bounds__(256, 2) void gemm_v(const _Float16* __restrict__ Ah_g,
                                                 const _Float16* __restrict__ Bh_g,
                                                 const float* __restrict__ bias,
                                                 _Float16* __restrict__ C) {
    __shared__ __align__(16) _Float16 lds[10240];
    gemm_body<1, 2>(Ah_g, Ah_g, Bh_g, Bh_g, bias, C, lds, blockIdx.x);
}

__global__ __launch_bounds__(256, 2) void gemm_o(const _Float16* __restrict__ Ah_g,
                                                 const _Float16* __restrict__ Bh_g,
                                                 const float* __restrict__ bias,
                                                 float* __restrict__ C) {
    __shared__ __align__(16) _Float16 lds[10240];
    gemm_body<1, 0>(Ah_g, Ah_g, Bh_g, Bh_g, bias, C, lds, blockIdx.x);
}

// ============== register-resident radix-8 DIF forward FFT (N=2048), fp32 in ==============
// 1024 blocks × 4 sequences. Product accumulator in registers. PAD3 keeps every
// exchange pattern at the b64 bank floor.
#define PAD3(i) ((i) + ((i) >> 3))

__device__ inline float2 cmul2(float2 a, float2 w) {
    return make_float2(a.x * w.x - a.y * w.y, a.x * w.y + a.y * w.x);
}
__device__ inline float2 cadd2(float2 a, float2 b) { return make_float2(a.x + b.x, a.y + b.y); }
__device__ inline float2 csub2(float2 a, float2 b) { return make_float2(a.x - b.x, a.y - b.y); }

__global__ __launch_bounds__(256) void fft_fwd(const float* __restrict__ qT,
                                               const float* __restrict__ kT,
                                               float* __restrict__ specP) {
    const int blk  = blockIdx.x;     // bh*16 + part
    const int bh   = blk >> 4;
    const int part = blk & 15;
    const int t    = threadIdx.x;
    __shared__ float2 Zs[2304];      // PAD3(2047) = 2302
    __shared__ float2 Wt[1024];      // Wt[j] = exp(-2*pi*i*j/2048)

#pragma unroll
    for (int s = 0; s < 4; s++) {
        const int j = t + s * 256;
        float sv, cv;
        __sincosf(2.0f * (float)M_PI * (float)j / 2048.0f, &sv, &cv);
        Wt[j] = make_float2(cv, -sv);
    }

    float2 pacc[8];
#pragma unroll
    for (int s = 0; s < 8; s++) pacc[s] = make_float2(0.0f, 0.0f);

    const int low5 = t & 31, hi3 = t >> 5;
    const int low2 = t & 3,  hi6 = t >> 2;

    for (int j4 = 0; j4 < 4; j4++) {
        const int seq = bh * 64 + part * 4 + j4;
        const float* qp = qT + (size_t)seq * 2048;
        const float* kp = kT + (size_t)seq * 2048;
        float2 z[8];
#pragma unroll
        for (int s = 0; s < 8; s++) z[s] = make_float2(qp[t + 256 * s], kp[t + 256 * s]);
        __syncthreads();   // Wt ready (iter 0); prev unpack reads done (iter >0)

        // ---- round 1 (bits 10,9,8), jb = t ----
#pragma unroll
        for (int sp = 0; sp < 4; sp++) {
            float2 u = z[sp], v = z[sp + 4];
            z[sp]     = cadd2(u, v);
            z[sp + 4] = cmul2(csub2(u, v), Wt[t + 256 * sp]);
        }
#pragma unroll
        for (int base = 0; base < 8; base += 4)
#pragma unroll
            for (int q2 = 0; q2 < 2; q2++) {
                float2 u = z[base + q2], v = z[base + q2 + 2];
                z[base + q2]     = cadd2(u, v);
                z[base + q2 + 2] = cmul2(csub2(u, v), Wt[2 * (t + 256 * q2)]);
            }
        {
            const float2 w = Wt[4 * t];
#pragma unroll
            for (int e = 0; e < 8; e += 2) {
                float2 u = z[e], v = z[e + 1];
                z[e]     = cadd2(u, v);
                z[e + 1] = cmul2(csub2(u, v), w);
            }
        }

        // exchange 1: (t+256s) -> (low5+32s+256hi3)
#pragma unroll
        for (int s = 0; s < 8; s++) Zs[PAD3(t + 256 * s)] = z[s];
        __syncthreads();
#pragma unroll
        for (int s = 0; s < 8; s++) z[s] = Zs[PAD3(low5 + 32 * s + 256 * hi3)];
        // no barrier: round-2 writes return to the same slots this thread read

        // ---- round 2 (bits 7,6,5), jb = low5 ----
#pragma unroll
        for (int sp = 0; sp < 4; sp++) {
            float2 u = z[sp], v = z[sp + 4];
            z[sp]     = cadd2(u, v);
            z[sp + 4] = cmul2(csub2(u, v), Wt[8 * (low5 + 32 * sp)]);
        }
#pragma unroll
        for (int base = 0; base < 8; base += 4)
#pragma unroll
            for (int q2 = 0; q2 < 2; q2++) {
                float2 u = z[base + q2], v = z[base + q2 + 2];
                z[base + q2]     = cadd2(u, v);
                z[base + q2 + 2] = cmul2(csub2(u, v), Wt[16 * (low5 + 32 * q2)]);
            }
        {
            const float2 w = Wt[32 * low5];
#pragma unroll
            for (int e = 0; e < 8; e += 2) {
                float2 u = z[e], v = z[e + 1];
                z[e]     = cadd2(u, v);
                z[e + 1] = cmul2(csub2(u, v), w);
            }
        }

        // exchange 2: (low5+32s+256hi3) -> (low2+4s+32hi6)
#pragma unroll
        for (int s = 0; s < 8; s++) Zs[PAD3(low5 + 32 * s + 256 * hi3)] = z[s];
        __syncthreads();
#pragma unroll
        for (int s = 0; s < 8; s++) z[s] = Zs[PAD3(low2 + 4 * s + 32 * hi6)];

        // ---- round 3 (bits 4,3,2), jb = low2 ----
#pragma unroll
        for (int sp = 0; sp < 4; sp++) {
            float2 u = z[sp], v = z[sp + 4];
            z[sp]     = cadd2(u, v);
            z[sp + 4] = cmul2(csub2(u, v), Wt[64 * (low2 + 4 * sp)]);
        }
#pragma unroll
        for (int base = 0; base < 8; base += 4)
#pragma unroll
            for (int q2 = 0; q2 < 2; q2++) {
                float2 u = z[base + q2], v = z[base + q2 + 2];
                z[base + q2]     = cadd2(u, v);
                z[base + q2 + 2] = cmul2(csub2(u, v), Wt[128 * (low2 + 4 * q2)]);
            }
        {
            const float2 w = Wt[256 * low2];
#pragma unroll
            for (int e = 0; e < 8; e += 2) {
                float2 u = z[e], v = z[e + 1];
                z[e]     = cadd2(u, v);
                z[e + 1] = cmul2(csub2(u, v), w);
            }
        }

        // exchange 3: (low2+4s+32hi6) -> (8t+s)
#pragma unroll
        for (int s = 0; s < 8; s++) Zs[PAD3(low2 + 4 * s + 32 * hi6)] = z[s];
        __syncthreads();
#pragma unroll
        for (int s = 0; s < 8; s++) z[s] = Zs[PAD3(8 * t + s)];

        // ---- round 4 (bits 1,0) ----
#pragma unroll
        for (int base = 0; base < 8; base += 4) {
            {
                float2 u = z[base], v = z[base + 2];
                z[base]     = cadd2(u, v);
                z[base + 2] = csub2(u, v);
            }
            {
                float2 u = z[base + 1], v = z[base + 3];
                float2 d = csub2(u, v);
                z[base + 1] = cadd2(u, v);
                z[base + 3] = make_float2(d.y, -d.x);
            }
        }
#pragma unroll
        for (int e = 0; e < 8; e += 2) {
            float2 u = z[e], v = z[e + 1];
            z[e]     = cadd2(u, v);
            z[e + 1] = csub2(u, v);
        }

        // write back completed FFT (same slots this thread read -> only one barrier)
#pragma unroll
        for (int s = 0; s < 8; s++) Zs[PAD3(8 * t + s)] = z[s];
        __syncthreads();

        // unpack q+ik; accumulate P at thread-fixed positions p = t+256s (registers)
#pragma unroll
        for (int s = 0; s < 8; s++) {
            const int p  = t + 256 * s;
            const int f  = (int)(__brev((unsigned)p) >> 21);
            const int fm = (2048 - f) & 2047;
            const int p2 = (int)(__brev((unsigned)fm) >> 21);
            const float2 zf = Zs[PAD3(p)];
            const float2 zm = Zs[PAD3(p2)];
            const float qr = 0.5f * (zf.x + zm.x);
            const float qi = 0.5f * (zf.y - zm.y);
            const float kr = 0.5f * (zf.y + zm.y);
            const float ki = 0.5f * (zm.x - zf.x);
            if (f != 0) {   // DC bin stays zero (mean subtraction)
                pacc[s].x += qr * kr + qi * ki;
                pacc[s].y += qi * kr - qr * ki;
            }
        }
    }

    // one coalesced partial-spectrum store (bit-rev position order)
    float2* outp = (float2*)specP + (size_t)blk * 2048;
#pragma unroll
    for (int s = 0; s < 8; s++) outp[t + 256 * s] = pacc[s];
}

// ---------------- inverse (DIT over bit-reversed input) + top-8 ----------------
__device__ inline void build_twiddle(float2* Wt, int tid, float sign) {
#pragma unroll
    for (int s = 0; s < 4; s++) {
        const int j = tid + s * 256;
        const float a = 2.0f * (float)M_PI * (float)j / 2048.0f;
        float sv, cv;
        __sincosf(a, &sv, &cv);
        Wt[j] = make_float2(cv, sign * sv);
    }
}

__device__ inline void fft2048_stages(float2* Z, const float2* Wt, int tid) {
    for (int st = 0; st < 11; st++) {
        const int half = 1 << st;
        const int shift = 10 - st;
#pragma unroll
        for (int r = 0; r < 4; r++) {
            const int m   = tid + r * 256;
            const int grp = m >> st;
            const int pos = m & (half - 1);
            const int i0  = (grp << (st + 1)) + pos;
            const int i1  = i0 + half;
            const float2 w = Wt[pos << shift];
            const float2 a = Z[i0];
            const float2 b = Z[i1];
            const float tr = b.x * w.x - b.y * w.y;
            const float ti = b.x * w.y + b.y * w.x;
            Z[i0] = make_float2(a.x + tr, a.y + ti);
            Z[i1] = make_float2(a.x - tr, a.y - ti);
        }
        __syncthreads();
    }
}

__global__ __launch_bounds__(256) void fft_inv_topk(const float* __restrict__ specP,
                                                    int* __restrict__ delays,
                                                    float* __restrict__ weights) {
    const int bh  = blockIdx.x;
    const int tid = threadIdx.x;
    __shared__ float2 Z[2048];
    __shared__ float2 Wt[1024];
    __shared__ float  corrS[2048];
    __shared__ float  rv[256];
    __shared__ int    ri[256];
    __shared__ float  vals[KD];
    __shared__ int    inds[KD];

    build_twiddle(Wt, tid, +1.0f);

    const float2* sp = (const float2*)specP + (size_t)bh * 16 * 2048;
#pragma unroll
    for (int s = 0; s < 8; s++) {
        const int p = tid + s * 256;
        float2 acc = make_float2(0.0f, 0.0f);
#pragma unroll
        for (int part = 0; part < 16; part++) {
            const float2 v = sp[part * 2048 + p];
            acc.x += v.x; acc.y += v.y;
        }
        Z[p] = acc;
    }
    __syncthreads();
    fft2048_stages(Z, Wt, tid);

    const float scale = 1.0f / (2048.0f * 64.0f);
#pragma unroll
    for (int s = 0; s < 8; s++) {
        const int i = tid + s * 256;
        corrS[i] = Z[i].x * scale;
    }
    __syncthreads();

    for (int k = 0; k < KD; k++) {
        float best = -1e30f;
        int   bi   = 1 << 30;
        for (int i = tid; i < 2048; i += 256) {
            const float v = corrS[i];
            if (v > best || (v == best && i < bi)) { best = v; bi = i; }
        }
        rv[tid] = best;
        ri[tid] = bi;
        __syncthreads();
        for (int off = 128; off > 0; off >>= 1) {
            if (tid < off) {
                const float v2 = rv[tid + off];
                const int   i2 = ri[tid + off];
                if (v2 > rv[tid] || (v2 == rv[tid] && i2 < ri[tid])) {
                    rv[tid] = v2; ri[tid] = i2;
                }
            }
            __syncthreads();
        }
        if (tid == 0) {
            vals[k] = rv[0];
            inds[k] = ri[0];
            corrS[ri[0]] = -1e30f;
        }
        __syncthreads();
    }

    if (tid == 0) {
        float sum = 0.0f;
        for (int k = 0; k < KD; k++) sum += vals[k];
        const float inv = 1.0f / (sum + 1e-12f);
        for (int k = 0; k < KD; k++) {
            weights[bh * KD + k] = vals[k] * inv;
            delays[bh * KD + k]  = inds[k];
        }
    }
}

// weighted circular-shift gather, fp16 in/out, 8 dh per thread (16B loads/stores)
__global__ __launch_bounds__(256) void gather_ws(const _Float16* __restrict__ v,
                                                 const int* __restrict__ delays,
                                                 const float* __restrict__ weights,
                                                 _Float16* __restrict__ outb) {
    const int gp = blockIdx.x * 256 + threadIdx.x;   // over M*64 = 1048576
    const int c8 = gp & 63;
    const int m  = gp >> 6;
    const int l  = m & 2047;
    const int b  = m >> 11;
    const int ch = c8 * 8;
    const int h  = ch >> 6;
    const int dh = ch & 63;
    const int bh = b * 8 + h;

    const _Float16* vb = v + (size_t)bh * 131072;
    float a[8] = {};
#pragma unroll
    for (int k = 0; k < KD; k++) {
        const int   d = delays[bh * KD + k];
        const float w = weights[bh * KD + k];
        const int   p = (l + d) & 2047;
        const f16x8 pv = *(const f16x8*)&vb[p * 64 + dh];
#pragma unroll
        for (int j = 0; j < 8; j++) a[j] = fmaf(w, (float)pv[j], a[j]);
    }
    f16x8 ov;
#pragma unroll
    for (int j = 0; j < 8; j++) ov[j] = (_Float16)a[j];
    *(f16x8*)&outb[(size_t)m * 512 + ch] = ov;
}

extern "C" void kernel_launch(void* const* d_in, const int* in_sizes, int n_in,
                              void* d_out, int out_size, void* d_ws, size_t ws_size,
                              hipStream_t stream) {
    const float* x_q  = (const float*)d_in[0];
    const float* x_kv = (const float*)d_in[1];
    const float* Wq   = (const float*)d_in[2];
    const float* bq   = (const float*)d_in[3];
    const float* Wk   = (const float*)d_in[4];
    const float* bk   = (const float*)d_in[5];
    const float* Wv   = (const float*)d_in[6];
    const float* bv   = (const float*)d_in[7];
    const float* Wo   = (const float*)d_in[8];
    const float* bo   = (const float*)d_in[9];
    float* out = (float*)d_out;

    // ---- workspace choreography (stream-ordered aliasing; peak 70.3 MB) ----
    char* ws = (char*)d_ws;
    _Float16* Xq_h  = (_Float16*)(ws + 0);           // 16 MiB (dead after qk-gemm)
    _Float16* Xq_l  = (_Float16*)(ws + 16777216);    // 16 MiB (dead after qk-gemm)
    _Float16* Xkv_h = (_Float16*)(ws + 33554432);    // 16 MiB (live until v-gemm)
    _Float16* Xkv_l = (_Float16*)(ws + 50331648);    // 16 MiB (dead after qk-gemm)
    _Float16* Wq_h  = (_Float16*)(ws + 67108864);
    _Float16* Wq_l  = (_Float16*)(ws + 67633152);
    _Float16* Wk_h  = (_Float16*)(ws + 68157440);
    _Float16* Wk_l  = (_Float16*)(ws + 68681728);
    _Float16* Wv_h  = (_Float16*)(ws + 69206016);
    _Float16* Wo_h  = (_Float16*)(ws + 69730304);
    int*      dely  = (int*)    (ws + 70254592);
    float*    wgt   = (float*)  (ws + 70256640);
    // aliases (each written only after the region underneath is dead):
    float*    kf32  = (float*)  (ws + 75497472);     // 32 MiB fresh region? NO — see below
    // NOTE: k output must not overwrite Xq (qk-gemm reads Xq while writing k).
    // Layout: kf32 goes over Xkv_l + the 5 MiB weight gap is too small, so kf32
    // gets its own region ABOVE the fp16 buffers; peak ws = 70.3 + 32 = 102.6 MB
    // exceeds proven 100.7 — instead put kf32 at +0 is ILLEGAL now.
    // Resolution: q writes to d_out (fp32), k writes over Xkv_l(16 MiB)+Xq_l? Xq_l
    // is read by q-blocks of the SAME dispatch — also illegal.
    // Final: kf32 lives in the upper half of d_out? d_out is 32 MiB total and q
    // needs all of it. So: kf32 = ws+70.3MB region (32 MiB) — requires ws >= 103 MB.
    // Fall back: if ws is smaller, the harness would have failed round 1 (we used
    // 100.7 MB there). 103 > 100.7: NOT safe. Therefore k keeps its own dispatch
    // ordering trick: kf32 over Xq (ws+0) is safe ONLY if k-gemm runs after q-gemm.
    // In the merged dispatch, q-blocks and k-blocks run CONCURRENTLY, so k must
    // write to memory disjoint from all gemm inputs: use specP region + beyond:
    // ws+50331648 (over Xkv_l, which IS read by k-blocks... also illegal).
    // => the merge requires 32 MiB of scratch disjoint from Xq_h/l, Xkv_h/l, W*.
    //    Only d_out qualifies, but q already uses it. Split d_out: q -> d_out
    //    (fp32, 32 MiB == exactly B*H*DH*L*4 = 33554432 B). d_out is 33554432 B
    //    total — q fills it exactly. No room for k.
    // Conclusion: write k as TWO fp16 arrays (hi16+lo16 of the fp32 value,
    // lossless split of fp32? no — fp16 pair is lossy).
    float*    specP = (float*)  (ws + 50331648);     // 16 MiB over Xkv_l (1024 partials)
    _Float16* vh    = (_Float16*)(ws + 0);           // 16 MiB over Xq_h (v-gemm after fft)
    _Float16* gbuf  = (_Float16*)(ws + 16777216);    // 16 MiB over Xq_l
    float*    qf32  = (float*)d_out;

    // ---- k storage: LOSSLESS fp32 split into two u16 planes (hi/lo halves of
    // the IEEE bits), reassembled in fft_fwd? That changes fft_fwd signature.
    // SIMPLER AND SAFE: keep q,k GEMMs SEPARATE (as round 7) — the merge is
    // dropped for k due to the aliasing constraint above. We still merge the
    // independent V GEMM with the QK pair? v reads Xkv_h + Wv_h and writes vh
    // (over Xq_h) — Xq_h is read by q-blocks of the same dispatch: illegal too.
    // => launch-merge abandoned; this round ships gather-f16x8 + k-gemm
    //    reordered AFTER fft-independent work to shrink critical path.
    (void)0;

    dim3 blk(256);

    prep_all<<<dim3(8704), blk, 0, stream>>>(x_q, x_kv, Wq, Wk, Wv, Wo,
                                             Xq_h, Xq_l, Xkv_h, Xkv_l,
                                             Wq_h, Wq_l, Wk_h, Wk_l, Wv_h, Wo_h);

    // q projection (hi/lo) -> fp32 [B,H,DH,L] in d_out
    gemm_qk<<<dim3(512), blk, 0, stream>>>(Xq_h, Xq_l, Wq_h, Wq_l, bq, qf32,
                                           Xq_h, Xq_l, Wq_h, Wq_l, bq, qf32);
    // k projection (hi/lo) -> fp32 over dead Xq region
    {
        float* kf32_ = (float*)(ws + 0);
        gemm_qk<<<dim3(512), blk, 0, stream>>>(Xkv_h, Xkv_l, Wk_h, Wk_l, bk, kf32_,
                                               Xkv_h, Xkv_l, Wk_h, Wk_l, bk, kf32_);
    }

    // forward FFTs: 1024 blocks × 4 sequences -> 16 partials/bh (no atomics)
    fft_fwd<<<dim3(1024), blk, 0, stream>>>(qf32, (float*)(ws + 0), specP);
    fft_inv_topk<<<dim3(BB * HH), blk, 0, stream>>>(specP, dely, wgt);

    // v projection (plain fp16) -> fp16 [B,H,L,DH], over dead Xq_h/kf32 low half
    gemm_v<<<dim3(512), blk, 0, stream>>>(Xkv_h, Wv_h, bv, vh);

    // weighted circular gather -> fp16 [B,L,D], over dead Xq_l/kf32 high half
    gather_ws<<<dim3(4096), blk, 0, stream>>>(vh, dely, wgt, gbuf);

    // final projection -> fp32 output (d_out; qf32 dead)
    gemm_o<<<dim3(512), blk, 0, stream>>>(gbuf, Wo_h, bo, out);
}